// Round 7
// baseline (513.696 us; speedup 1.0000x reference)
//
#include <hip/hip_runtime.h>
#include <math.h>

#define N_NODES 100000
#define N_EDGES 1000000
#define D 64
#define N_CONVS 6
#define CAP 64  // max degree bucket (Poisson(10): P(deg>64) ~ 1e-30/node)
#define NDTOT (N_NODES * D)

typedef __bf16 bf16x8 __attribute__((ext_vector_type(8)));
typedef float f32x4 __attribute__((ext_vector_type(4)));

static __device__ __forceinline__ float hi2f(unsigned int d) {
    union { unsigned int i; float f; } c; c.i = d & 0xFFFF0000u; return c.f;
}
static __device__ __forceinline__ float lo2f(unsigned int d) {
    union { unsigned int i; float f; } c; c.i = d << 16; return c.f;
}
static __device__ __forceinline__ unsigned short f2bf(float f) {
    union { float f; unsigned int i; } c; c.f = f;
    unsigned int x = c.i;
    unsigned int r = (x + 0x7fffu + ((x >> 16) & 1u)) >> 16;
    return (unsigned short)r;
}

// ---------------- bucket-CSR build: 4 edges/thread for MLP ----------------

__global__ void fill_cap(const int* __restrict__ src, const int* __restrict__ dst, int E,
                         int* __restrict__ cnt, int* __restrict__ colIdx) {
    int e0 = (blockIdx.x * 256 + threadIdx.x) * 4;
    if (e0 + 3 < E) {
        const int4 d4 = *(const int4*)&dst[e0];
        const int4 s4 = *(const int4*)&src[e0];
        int t0 = atomicAdd(&cnt[d4.x], 1);
        int t1 = atomicAdd(&cnt[d4.y], 1);
        int t2 = atomicAdd(&cnt[d4.z], 1);
        int t3 = atomicAdd(&cnt[d4.w], 1);
        if (t0 < CAP) colIdx[(size_t)d4.x * CAP + t0] = s4.x;
        if (t1 < CAP) colIdx[(size_t)d4.y * CAP + t1] = s4.y;
        if (t2 < CAP) colIdx[(size_t)d4.z * CAP + t2] = s4.z;
        if (t3 < CAP) colIdx[(size_t)d4.w * CAP + t3] = s4.w;
    } else {
        for (int e = e0; e < E; ++e) {
            int d = dst[e];
            int slot = atomicAdd(&cnt[d], 1);
            if (slot < CAP) colIdx[(size_t)d * CAP + slot] = src[e];
        }
    }
}

// ---------------- prep: fp32->bf16 converts + weight prepack, one launch ----------------

__global__ void prep_all(const float* __restrict__ x, const float* __restrict__ h,
                         unsigned short* __restrict__ xb, unsigned short* __restrict__ hb,
                         const float* __restrict__ Wq, const float* __restrict__ Wk,
                         const float* __restrict__ Wv, const float* __restrict__ Ws,
                         const float* __restrict__ bq, const float* __restrict__ bk,
                         const float* __restrict__ bv, const float* __restrict__ bs,
                         unsigned short* __restrict__ WT, float* __restrict__ ball,
                         int nCvt) {
    int b = blockIdx.x;
    if (b < nCvt) {
        int i = (b * 256 + threadIdx.x) * 4;
        if (i < NDTOT) {
            float4 fx = *(const float4*)&x[i];
            float4 fh = *(const float4*)&h[i];
            ushort4 ux, uh;
            ux.x = f2bf(fx.x); ux.y = f2bf(fx.y); ux.z = f2bf(fx.z); ux.w = f2bf(fx.w);
            uh.x = f2bf(fh.x); uh.y = f2bf(fh.y); uh.z = f2bf(fh.z); uh.w = f2bf(fh.w);
            *(ushort4*)&xb[i] = ux;
            *(ushort4*)&hb[i] = uh;
        }
    } else {
        int idx = (b - nCvt) * 256 + threadIdx.x;   // conv*16384 + n*64 + k
        if (idx >= N_CONVS * 256 * 64) return;
        int conv = idx >> 14;
        int rem = idx & 16383;
        int n = rem >> 6, kk = rem & 63;
        int mat = n >> 6, c = n & 63;
        const float* W = mat == 0 ? Wq : mat == 1 ? Wk : mat == 2 ? Wv : Ws;
        WT[idx] = f2bf(W[conv * 4096 + kk * 64 + c]);
        if (kk == 0) {
            const float* B = mat == 0 ? bq : mat == 1 ? bk : mat == 2 ? bv : bs;
            ball[conv * 256 + n] = B[conv * 64 + c];
        }
    }
}

// ---------------- pair GEMM: convA(XA) & convB(XB), swapped-operand MFMA ----------------
// 512 threads = 8 waves. wave = conv*4 + mat; mat 0..2 -> q/k/v, mat 3 -> skip.
// mfma(Wfrag, Xfrag): D col (l&15) = node row m, D reg r -> output col n = lhi*4+r.

static __device__ __forceinline__ void gemm_pair_body(
    const unsigned short* __restrict__ XA, const unsigned short* __restrict__ XB, int N,
    const unsigned short* __restrict__ WTA, const unsigned short* __restrict__ WTB,
    const float* __restrict__ ballA, const float* __restrict__ ballB,
    unsigned short* __restrict__ qA, unsigned short* __restrict__ kvA,
    unsigned short* __restrict__ qB, unsigned short* __restrict__ kvB,
    float* __restrict__ sk)
{
    __shared__ __align__(16) unsigned short XLA[64][72];
    __shared__ __align__(16) unsigned short XLB[64][72];
    __shared__ __align__(16) float SKIP[64][68];

    const int tid = threadIdx.x;
    const int base = blockIdx.x * 64;
    const int lane = tid & 63;
    const int wave = tid >> 6;
    const int conv = wave >> 2;
    const int mat = wave & 3;

    {
        int r = tid >> 3, cc = (tid & 7) * 8;
        uint4 va = {0u,0u,0u,0u}, vb = {0u,0u,0u,0u};
        if (base + r < N) {
            va = *(const uint4*)&XA[(size_t)(base + r) * D + cc];
            vb = *(const uint4*)&XB[(size_t)(base + r) * D + cc];
        }
        *(uint4*)&XLA[r][cc] = va;
        *(uint4*)&XLB[r][cc] = vb;
    }
    __syncthreads();

    const int l15 = lane & 15;
    const int lhi = lane >> 4;
    const int n0 = mat * 64;
    const unsigned short* WT = conv ? WTB : WTA;
    const float* ball = conv ? ballB : ballA;

    bf16x8 Wf[4][2];
#pragma unroll
    for (int ni = 0; ni < 4; ++ni)
#pragma unroll
        for (int ks = 0; ks < 2; ++ks)
            Wf[ni][ks] = *(const bf16x8*)&WT[(size_t)(n0 + ni * 16 + l15) * D + lhi * 8 + ks * 32];

    bf16x8 Xf[4][2];
#pragma unroll
    for (int mi = 0; mi < 4; ++mi)
#pragma unroll
        for (int ks = 0; ks < 2; ++ks)
            Xf[mi][ks] = conv ? *(const bf16x8*)&XLB[mi * 16 + l15][lhi * 8 + ks * 32]
                              : *(const bf16x8*)&XLA[mi * 16 + l15][lhi * 8 + ks * 32];

    f32x4 acc[4][4];
#pragma unroll
    for (int ni = 0; ni < 4; ++ni) {
        const float4 b4 = *(const float4*)&ball[n0 + ni * 16 + lhi * 4];
#pragma unroll
        for (int mi = 0; mi < 4; ++mi) {
            f32x4 t;
            t[0] = b4.x; t[1] = b4.y; t[2] = b4.z; t[3] = b4.w;
            acc[mi][ni] = t;
        }
    }

#pragma unroll
    for (int ks = 0; ks < 2; ++ks)
#pragma unroll
        for (int mi = 0; mi < 4; ++mi)
#pragma unroll
            for (int ni = 0; ni < 4; ++ni)
                acc[mi][ni] = __builtin_amdgcn_mfma_f32_16x16x32_bf16(
                    Wf[ni][ks], Xf[mi][ks], acc[mi][ni], 0, 0, 0);

    if (mat < 3) {
        unsigned short* qX = conv ? qB : qA;
        unsigned short* kvX = conv ? kvB : kvA;
#pragma unroll
        for (int mi = 0; mi < 4; ++mi) {
            int row = base + mi * 16 + l15;
            if (row < N) {
#pragma unroll
                for (int ni = 0; ni < 4; ++ni) {
                    int col = ni * 16 + lhi * 4;
                    ushort4 u;
                    u.x = f2bf(acc[mi][ni][0]); u.y = f2bf(acc[mi][ni][1]);
                    u.z = f2bf(acc[mi][ni][2]); u.w = f2bf(acc[mi][ni][3]);
                    if (mat == 0)      *(ushort4*)&qX[(size_t)row * 64 + col] = u;
                    else if (mat == 1) *(ushort4*)&kvX[(size_t)row * 128 + col] = u;
                    else               *(ushort4*)&kvX[(size_t)row * 128 + 64 + col] = u;
                }
            }
        }
    } else if (conv == 0) {
#pragma unroll
        for (int mi = 0; mi < 4; ++mi)
#pragma unroll
            for (int ni = 0; ni < 4; ++ni)
                *(f32x4*)&SKIP[mi * 16 + l15][ni * 16 + lhi * 4] = acc[mi][ni];
    }
    __syncthreads();
    if (mat == 3 && conv == 1) {
#pragma unroll
        for (int mi = 0; mi < 4; ++mi) {
            int row = base + mi * 16 + l15;
            if (row < N) {
#pragma unroll
                for (int ni = 0; ni < 4; ++ni) {
                    int col = ni * 16 + lhi * 4;
                    const f32x4 s4 = *(const f32x4*)&SKIP[mi * 16 + l15][col];
                    float4 r4;
                    r4.x = acc[mi][ni][0] + s4[0];
                    r4.y = acc[mi][ni][1] + s4[1];
                    r4.z = acc[mi][ni][2] + s4[2];
                    r4.w = acc[mi][ni][3] + s4[3];
                    *(float4*)&sk[(size_t)row * 64 + col] = r4;
                }
            }
        }
    }
}

__global__ __launch_bounds__(512) void gemm_pair(
    const unsigned short* __restrict__ XA, const unsigned short* __restrict__ XB, int N,
    const unsigned short* __restrict__ WTA, const unsigned short* __restrict__ WTB,
    const float* __restrict__ ballA, const float* __restrict__ ballB,
    unsigned short* __restrict__ qA, unsigned short* __restrict__ kvA,
    unsigned short* __restrict__ qB, unsigned short* __restrict__ kvB,
    float* __restrict__ sk)
{
    gemm_pair_body(XA, XB, N, WTA, WTB, ballA, ballB, qA, kvA, qB, kvB, sk);
}

// ---------------- dual-conv edge attention: one 8-lane group per NODE ----------------
// block = 256 thr = 32 nodes. Group's 8 lanes each own 8 feats (t*8..t*8+7); the group
// walks its node's bucket 1 edge/step. Dot reduce = 3 intra-group shfls (doubles as
// broadcast). No cross-group reduce at all. No-max softmax: scores bounded, exp2 safe.

__global__ __launch_bounds__(256) void edge_attn2(
    const int* __restrict__ cnt, const int* __restrict__ colIdx,
    const unsigned short* __restrict__ q0, const unsigned short* __restrict__ kv0,
    const unsigned short* __restrict__ q1, const unsigned short* __restrict__ kv1,
    float* __restrict__ tgt, int N)
{
    const int tid = threadIdx.x;
    const int node = blockIdx.x * 32 + (tid >> 3);
    if (node >= N) return;
    const int t = tid & 7;

    int deg = cnt[node];
    if (deg > CAP) deg = CAP;

    const float SC = 0.18033688f;  // 0.125 * log2(e)
    const uint4 qa4 = *(const uint4*)&q0[(size_t)node * 64 + t * 8];
    const uint4 qb4 = *(const uint4*)&q1[(size_t)node * 64 + t * 8];
    float qa[8], qb[8];
    qa[0] = lo2f(qa4.x) * SC; qa[1] = hi2f(qa4.x) * SC;
    qa[2] = lo2f(qa4.y) * SC; qa[3] = hi2f(qa4.y) * SC;
    qa[4] = lo2f(qa4.z) * SC; qa[5] = hi2f(qa4.z) * SC;
    qa[6] = lo2f(qa4.w) * SC; qa[7] = hi2f(qa4.w) * SC;
    qb[0] = lo2f(qb4.x) * SC; qb[1] = hi2f(qb4.x) * SC;
    qb[2] = lo2f(qb4.y) * SC; qb[3] = hi2f(qb4.y) * SC;
    qb[4] = lo2f(qb4.z) * SC; qb[5] = hi2f(qb4.z) * SC;
    qb[6] = lo2f(qb4.w) * SC; qb[7] = hi2f(qb4.w) * SC;

    const size_t rowbase = (size_t)node * CAP;

    float l0 = 0.0f, l1 = 0.0f;
    float a0[8], a1[8];
#pragma unroll
    for (int i = 0; i < 8; ++i) { a0[i] = 0.0f; a1[i] = 0.0f; }

    for (int j = 0; j < deg; ++j) {
        const int s = colIdx[rowbase + j];   // uniform within group (HW broadcast)
        const unsigned short* pc0 = &kv0[(size_t)s * 128 + t * 8];
        const unsigned short* pc1 = &kv1[(size_t)s * 128 + t * 8];
        const uint4 uk0 = *(const uint4*)pc0;
        const uint4 uv0 = *(const uint4*)(pc0 + 64);
        const uint4 uk1 = *(const uint4*)pc1;
        const uint4 uv1 = *(const uint4*)(pc1 + 64);

        float p0 = qa[0] * lo2f(uk0.x) + qa[1] * hi2f(uk0.x) + qa[2] * lo2f(uk0.y) + qa[3] * hi2f(uk0.y)
                 + qa[4] * lo2f(uk0.z) + qa[5] * hi2f(uk0.z) + qa[6] * lo2f(uk0.w) + qa[7] * hi2f(uk0.w);
        float p1 = qb[0] * lo2f(uk1.x) + qb[1] * hi2f(uk1.x) + qb[2] * lo2f(uk1.y) + qb[3] * hi2f(uk1.y)
                 + qb[4] * lo2f(uk1.z) + qb[5] * hi2f(uk1.z) + qb[6] * lo2f(uk1.w) + qb[7] * hi2f(uk1.w);
        p0 += __shfl_xor(p0, 1); p1 += __shfl_xor(p1, 1);
        p0 += __shfl_xor(p0, 2); p1 += __shfl_xor(p1, 2);
        p0 += __shfl_xor(p0, 4); p1 += __shfl_xor(p1, 4);
        const float w0 = exp2f(p0);
        const float w1 = exp2f(p1);
        l0 += w0; l1 += w1;
        a0[0] += w0 * lo2f(uv0.x); a0[1] += w0 * hi2f(uv0.x);
        a0[2] += w0 * lo2f(uv0.y); a0[3] += w0 * hi2f(uv0.y);
        a0[4] += w0 * lo2f(uv0.z); a0[5] += w0 * hi2f(uv0.z);
        a0[6] += w0 * lo2f(uv0.w); a0[7] += w0 * hi2f(uv0.w);
        a1[0] += w1 * lo2f(uv1.x); a1[1] += w1 * hi2f(uv1.x);
        a1[2] += w1 * lo2f(uv1.y); a1[3] += w1 * hi2f(uv1.y);
        a1[4] += w1 * lo2f(uv1.z); a1[5] += w1 * hi2f(uv1.z);
        a1[6] += w1 * lo2f(uv1.w); a1[7] += w1 * hi2f(uv1.w);
    }

    const float inv0 = 1.0f / (l0 + 1e-16f);
    const float inv1 = 1.0f / (l1 + 1e-16f);
    float* pout = &tgt[(size_t)node * 64 + t * 8];
    float4 o1 = *(float4*)pout;
    float4 o2 = *(float4*)(pout + 4);
    o1.x += a0[0] * inv0 + a1[0] * inv1;
    o1.y += a0[1] * inv0 + a1[1] * inv1;
    o1.z += a0[2] * inv0 + a1[2] * inv1;
    o1.w += a0[3] * inv0 + a1[3] * inv1;
    o2.x += a0[4] * inv0 + a1[4] * inv1;
    o2.y += a0[5] * inv0 + a1[5] * inv1;
    o2.z += a0[6] * inv0 + a1[6] * inv1;
    o2.w += a0[7] * inv0 + a1[7] * inv1;
    *(float4*)pout = o1;
    *(float4*)(pout + 4) = o2;
}

// ---------------- elementwise (vectorized x4) ----------------

__global__ void rh_kernel(const float* __restrict__ rpre, const float* __restrict__ h,
                          unsigned short* __restrict__ rhb, int n) {
    int i = (blockIdx.x * 256 + threadIdx.x) * 4;
    if (i < n) {
        float4 rp = *(const float4*)&rpre[i];
        float4 hh = *(const float4*)&h[i];
        ushort4 o;
        o.x = f2bf(hh.x / (1.0f + __expf(-rp.x)));
        o.y = f2bf(hh.y / (1.0f + __expf(-rp.y)));
        o.z = f2bf(hh.z / (1.0f + __expf(-rp.z)));
        o.w = f2bf(hh.w / (1.0f + __expf(-rp.w)));
        *(ushort4*)&rhb[i] = o;
    }
}

__global__ void final_kernel(const float* __restrict__ zpre, const float* __restrict__ h,
                             const float* __restrict__ c45, float* __restrict__ out, int n) {
    int i = (blockIdx.x * 256 + threadIdx.x) * 4;
    if (i < n) {
        float4 zp = *(const float4*)&zpre[i];
        float4 hh = *(const float4*)&h[i];
        float4 cc = *(const float4*)&c45[i];
        float4 r;
        float z0 = 1.0f / (1.0f + __expf(-zp.x));
        float z1 = 1.0f / (1.0f + __expf(-zp.y));
        float z2 = 1.0f / (1.0f + __expf(-zp.z));
        float z3 = 1.0f / (1.0f + __expf(-zp.w));
        r.x = z0 * hh.x + (1.0f - z0) * tanhf(cc.x);
        r.y = z1 * hh.y + (1.0f - z1) * tanhf(cc.y);
        r.z = z2 * hh.z + (1.0f - z2) * tanhf(cc.z);
        r.w = z3 * hh.w + (1.0f - z3) * tanhf(cc.w);
        *(float4*)&out[i] = r;
    }
}

// ---------------- launch ----------------

extern "C" void kernel_launch(void* const* d_in, const int* in_sizes, int n_in,
                              void* d_out, int out_size, void* d_ws, size_t ws_size,
                              hipStream_t stream) {
    const int N = N_NODES, E = N_EDGES;
    const float* x  = (const float*)d_in[0];
    const float* h  = (const float*)d_in[1];
    const int*  ei  = (const int*)d_in[2];
    const float* Wq = (const float*)d_in[3];
    const float* bq = (const float*)d_in[4];
    const float* Wk = (const float*)d_in[5];
    const float* bk = (const float*)d_in[6];
    const float* Wv = (const float*)d_in[7];
    const float* bv = (const float*)d_in[8];
    const float* Ws = (const float*)d_in[9];
    const float* bs = (const float*)d_in[10];
    float* out = (float*)d_out;

    const int* src = ei;
    const int* dst = ei + E;

    // ---- workspace layout ----
    char* w = (char*)d_ws;
    int* cnt    = (int*)w;                        // N
    int* colIdx = cnt + N;                        // N*CAP
    size_t intWords = (size_t)N + (size_t)N * CAP;
    char* p = w + ((intWords * 4 + 255) & ~(size_t)255);

    const size_t ND = (size_t)N * D;
    float* zpre = (float*)p;            p += ND * 4;
    float* rpre = (float*)p;            p += ND * 4;
    float* c45  = (float*)p;            p += ND * 4;
    float* ball = (float*)p;            p += N_CONVS * 256 * 4;
    unsigned short* xb  = (unsigned short*)p; p += ND * 2;
    unsigned short* hb  = (unsigned short*)p; p += ND * 2;
    unsigned short* rhb = (unsigned short*)p; p += ND * 2;
    unsigned short* q0  = (unsigned short*)p; p += ND * 2;
    unsigned short* q1  = (unsigned short*)p; p += ND * 2;
    unsigned short* kv0 = (unsigned short*)p; p += ND * 2 * 2;
    unsigned short* kv1 = (unsigned short*)p; p += ND * 2 * 2;
    unsigned short* WT  = (unsigned short*)p; p += (size_t)N_CONVS * 256 * 64 * 2;

    const int NB_CVT = (int)(ND / 4 / 256);             // 6250 (exact)
    const int NB_PP = (N_CONVS * 256 * 64 + 255) / 256; // 384
    const int NB_GEMM = (N + 63) / 64;                  // 1563
    const int NB_E4 = (E / 4 + 255) / 256;              // 977
    const int NB_ATTN = (N + 31) / 32;                  // 3125
    const int NB_EW = (int)(ND / 4 / 256);              // 6250

    prep_all<<<NB_CVT + NB_PP, 256, 0, stream>>>(x, h, xb, hb, Wq, Wk, Wv, Ws,
                                                 bq, bk, bv, bs, WT, ball, NB_CVT);
    hipMemsetAsync(cnt, 0, (size_t)N * sizeof(int), stream);
    fill_cap<<<NB_E4, 256, 0, stream>>>(src, dst, E, cnt, colIdx);

#define WTc(i) (WT + (size_t)(i) * 256 * 64)
#define BLc(i) (ball + (size_t)(i) * 256)

    // pair (0,1) -> zpre
    gemm_pair<<<NB_GEMM, 512, 0, stream>>>(
        xb, hb, N, WTc(0), WTc(1), BLc(0), BLc(1), q0, kv0, q1, kv1, zpre);
    edge_attn2<<<NB_ATTN, 256, 0, stream>>>(cnt, colIdx, q0, kv0, q1, kv1, zpre, N);

    // pair (2,3) -> rpre
    gemm_pair<<<NB_GEMM, 512, 0, stream>>>(
        xb, hb, N, WTc(2), WTc(3), BLc(2), BLc(3), q0, kv0, q1, kv1, rpre);
    edge_attn2<<<NB_ATTN, 256, 0, stream>>>(cnt, colIdx, q0, kv0, q1, kv1, rpre, N);

    // rh, then pair (4,5) -> c45
    rh_kernel<<<NB_EW, 256, 0, stream>>>(rpre, h, rhb, (int)ND);
    gemm_pair<<<NB_GEMM, 512, 0, stream>>>(
        xb, rhb, N, WTc(4), WTc(5), BLc(4), BLc(5), q0, kv0, q1, kv1, c45);
    edge_attn2<<<NB_ATTN, 256, 0, stream>>>(cnt, colIdx, q0, kv0, q1, kv1, c45, N);

    final_kernel<<<NB_EW, 256, 0, stream>>>(zpre, h, c45, out, (int)ND);

#undef WTc
#undef BLc
}

// Round 8
// 501.222 us; speedup vs baseline: 1.0249x; 1.0249x over previous
//
#include <hip/hip_runtime.h>
#include <math.h>

#define N_NODES 100000
#define N_EDGES 1000000
#define D 64
#define N_CONVS 6
#define CAP 64  // max degree bucket (Poisson(10): P(deg>64) ~ 1e-30/node)
#define NDTOT (N_NODES * D)

typedef __bf16 bf16x8 __attribute__((ext_vector_type(8)));
typedef float f32x4 __attribute__((ext_vector_type(4)));

static __device__ __forceinline__ float hi2f(unsigned int d) {
    union { unsigned int i; float f; } c; c.i = d & 0xFFFF0000u; return c.f;
}
static __device__ __forceinline__ float lo2f(unsigned int d) {
    union { unsigned int i; float f; } c; c.i = d << 16; return c.f;
}
static __device__ __forceinline__ unsigned short f2bf(float f) {
    union { float f; unsigned int i; } c; c.f = f;
    unsigned int x = c.i;
    unsigned int r = (x + 0x7fffu + ((x >> 16) & 1u)) >> 16;
    return (unsigned short)r;
}

// ---------------- bucket-CSR build: 4 edges/thread for MLP ----------------

__global__ void fill_cap(const int* __restrict__ src, const int* __restrict__ dst, int E,
                         int* __restrict__ cnt, int* __restrict__ colIdx) {
    int e0 = (blockIdx.x * 256 + threadIdx.x) * 4;
    if (e0 + 3 < E) {
        const int4 d4 = *(const int4*)&dst[e0];
        const int4 s4 = *(const int4*)&src[e0];
        int t0 = atomicAdd(&cnt[d4.x], 1);
        int t1 = atomicAdd(&cnt[d4.y], 1);
        int t2 = atomicAdd(&cnt[d4.z], 1);
        int t3 = atomicAdd(&cnt[d4.w], 1);
        if (t0 < CAP) colIdx[(size_t)d4.x * CAP + t0] = s4.x;
        if (t1 < CAP) colIdx[(size_t)d4.y * CAP + t1] = s4.y;
        if (t2 < CAP) colIdx[(size_t)d4.z * CAP + t2] = s4.z;
        if (t3 < CAP) colIdx[(size_t)d4.w * CAP + t3] = s4.w;
    } else {
        for (int e = e0; e < E; ++e) {
            int d = dst[e];
            int slot = atomicAdd(&cnt[d], 1);
            if (slot < CAP) colIdx[(size_t)d * CAP + slot] = src[e];
        }
    }
}

// ---------------- prep: fp32->bf16 converts + weight prepack, one launch ----------------

__global__ void prep_all(const float* __restrict__ x, const float* __restrict__ h,
                         unsigned short* __restrict__ xb, unsigned short* __restrict__ hb,
                         const float* __restrict__ Wq, const float* __restrict__ Wk,
                         const float* __restrict__ Wv, const float* __restrict__ Ws,
                         const float* __restrict__ bq, const float* __restrict__ bk,
                         const float* __restrict__ bv, const float* __restrict__ bs,
                         unsigned short* __restrict__ WT, float* __restrict__ ball,
                         int nCvt) {
    int b = blockIdx.x;
    if (b < nCvt) {
        int i = (b * 256 + threadIdx.x) * 4;
        if (i < NDTOT) {
            float4 fx = *(const float4*)&x[i];
            float4 fh = *(const float4*)&h[i];
            ushort4 ux, uh;
            ux.x = f2bf(fx.x); ux.y = f2bf(fx.y); ux.z = f2bf(fx.z); ux.w = f2bf(fx.w);
            uh.x = f2bf(fh.x); uh.y = f2bf(fh.y); uh.z = f2bf(fh.z); uh.w = f2bf(fh.w);
            *(ushort4*)&xb[i] = ux;
            *(ushort4*)&hb[i] = uh;
        }
    } else {
        int idx = (b - nCvt) * 256 + threadIdx.x;   // conv*16384 + n*64 + k
        if (idx >= N_CONVS * 256 * 64) return;
        int conv = idx >> 14;
        int rem = idx & 16383;
        int n = rem >> 6, kk = rem & 63;
        int mat = n >> 6, c = n & 63;
        const float* W = mat == 0 ? Wq : mat == 1 ? Wk : mat == 2 ? Wv : Ws;
        WT[idx] = f2bf(W[conv * 4096 + kk * 64 + c]);
        if (kk == 0) {
            const float* B = mat == 0 ? bq : mat == 1 ? bk : mat == 2 ? bv : bs;
            ball[conv * 256 + n] = B[conv * 64 + c];
        }
    }
}

// ---------------- pair GEMM: convA(XA) & convB(XB), swapped-operand MFMA ----------------
// 512 threads = 8 waves. wave = conv*4 + mat; mat 0..2 -> q/k/v, mat 3 -> skip.
// Merged outputs: qboth[node][128] = qA|qB ; kvboth[node][256] = kA|vA|kB|vB.

static __device__ __forceinline__ void gemm_pair_body(
    const unsigned short* __restrict__ XA, const unsigned short* __restrict__ XB, int N,
    const unsigned short* __restrict__ WTA, const unsigned short* __restrict__ WTB,
    const float* __restrict__ ballA, const float* __restrict__ ballB,
    unsigned short* __restrict__ qboth, unsigned short* __restrict__ kvboth,
    float* __restrict__ sk)
{
    __shared__ __align__(16) unsigned short XLA[64][72];
    __shared__ __align__(16) unsigned short XLB[64][72];
    __shared__ __align__(16) float SKIP[64][68];

    const int tid = threadIdx.x;
    const int base = blockIdx.x * 64;
    const int lane = tid & 63;
    const int wave = tid >> 6;
    const int conv = wave >> 2;
    const int mat = wave & 3;

    {
        int r = tid >> 3, cc = (tid & 7) * 8;
        uint4 va = {0u,0u,0u,0u}, vb = {0u,0u,0u,0u};
        if (base + r < N) {
            va = *(const uint4*)&XA[(size_t)(base + r) * D + cc];
            vb = *(const uint4*)&XB[(size_t)(base + r) * D + cc];
        }
        *(uint4*)&XLA[r][cc] = va;
        *(uint4*)&XLB[r][cc] = vb;
    }
    __syncthreads();

    const int l15 = lane & 15;
    const int lhi = lane >> 4;
    const int n0 = mat * 64;
    const unsigned short* WT = conv ? WTB : WTA;
    const float* ball = conv ? ballB : ballA;

    bf16x8 Wf[4][2];
#pragma unroll
    for (int ni = 0; ni < 4; ++ni)
#pragma unroll
        for (int ks = 0; ks < 2; ++ks)
            Wf[ni][ks] = *(const bf16x8*)&WT[(size_t)(n0 + ni * 16 + l15) * D + lhi * 8 + ks * 32];

    bf16x8 Xf[4][2];
#pragma unroll
    for (int mi = 0; mi < 4; ++mi)
#pragma unroll
        for (int ks = 0; ks < 2; ++ks)
            Xf[mi][ks] = conv ? *(const bf16x8*)&XLB[mi * 16 + l15][lhi * 8 + ks * 32]
                              : *(const bf16x8*)&XLA[mi * 16 + l15][lhi * 8 + ks * 32];

    f32x4 acc[4][4];
#pragma unroll
    for (int ni = 0; ni < 4; ++ni) {
        const float4 b4 = *(const float4*)&ball[n0 + ni * 16 + lhi * 4];
#pragma unroll
        for (int mi = 0; mi < 4; ++mi) {
            f32x4 t;
            t[0] = b4.x; t[1] = b4.y; t[2] = b4.z; t[3] = b4.w;
            acc[mi][ni] = t;
        }
    }

#pragma unroll
    for (int ks = 0; ks < 2; ++ks)
#pragma unroll
        for (int mi = 0; mi < 4; ++mi)
#pragma unroll
            for (int ni = 0; ni < 4; ++ni)
                acc[mi][ni] = __builtin_amdgcn_mfma_f32_16x16x32_bf16(
                    Wf[ni][ks], Xf[mi][ks], acc[mi][ni], 0, 0, 0);

    if (mat < 3) {
        // q -> qboth[row*128 + conv*64 + col]
        // k -> kvboth[row*256 + conv*128 + col] ; v -> +64
        unsigned short* outb = (mat == 0) ? (qboth + conv * 64)
                                          : (kvboth + conv * 128 + (mat == 2 ? 64 : 0));
        const size_t rstride = (mat == 0) ? 128 : 256;
#pragma unroll
        for (int mi = 0; mi < 4; ++mi) {
            int row = base + mi * 16 + l15;
            if (row < N) {
#pragma unroll
                for (int ni = 0; ni < 4; ++ni) {
                    int col = ni * 16 + lhi * 4;
                    ushort4 u;
                    u.x = f2bf(acc[mi][ni][0]); u.y = f2bf(acc[mi][ni][1]);
                    u.z = f2bf(acc[mi][ni][2]); u.w = f2bf(acc[mi][ni][3]);
                    *(ushort4*)&outb[(size_t)row * rstride + col] = u;
                }
            }
        }
    } else if (conv == 0) {
#pragma unroll
        for (int mi = 0; mi < 4; ++mi)
#pragma unroll
            for (int ni = 0; ni < 4; ++ni)
                *(f32x4*)&SKIP[mi * 16 + l15][ni * 16 + lhi * 4] = acc[mi][ni];
    }
    __syncthreads();
    if (mat == 3 && conv == 1) {
#pragma unroll
        for (int mi = 0; mi < 4; ++mi) {
            int row = base + mi * 16 + l15;
            if (row < N) {
#pragma unroll
                for (int ni = 0; ni < 4; ++ni) {
                    int col = ni * 16 + lhi * 4;
                    const f32x4 s4 = *(const f32x4*)&SKIP[mi * 16 + l15][col];
                    float4 r4;
                    r4.x = acc[mi][ni][0] + s4[0];
                    r4.y = acc[mi][ni][1] + s4[1];
                    r4.z = acc[mi][ni][2] + s4[2];
                    r4.w = acc[mi][ni][3] + s4[3];
                    *(float4*)&sk[(size_t)row * 64 + col] = r4;
                }
            }
        }
    }
}

__global__ __launch_bounds__(512) void gemm_pair(
    const unsigned short* __restrict__ XA, const unsigned short* __restrict__ XB, int N,
    const unsigned short* __restrict__ WTA, const unsigned short* __restrict__ WTB,
    const float* __restrict__ ballA, const float* __restrict__ ballB,
    unsigned short* __restrict__ qboth, unsigned short* __restrict__ kvboth,
    float* __restrict__ sk)
{
    gemm_pair_body(XA, XB, N, WTA, WTB, ballA, ballB, qboth, kvboth, sk);
}

// ---------------- dual-conv edge attention: 8-lane group per node, 2 edges/iter ----------
// Per edge the group reads one CONTIGUOUS 512B block (k0|v0|k1|v1). Unroll-2 doubles
// loads in flight per lane. Dot reduce = 3 intra-group shfls. No cross-group reduce.

__global__ __launch_bounds__(256) void edge_attn2(
    const int* __restrict__ cnt, const int* __restrict__ colIdx,
    const unsigned short* __restrict__ qboth, const unsigned short* __restrict__ kvboth,
    float* __restrict__ tgt, int N)
{
    const int tid = threadIdx.x;
    const int node = blockIdx.x * 32 + (tid >> 3);
    if (node >= N) return;
    const int t = tid & 7;

    int deg = cnt[node];
    if (deg > CAP) deg = CAP;

    const float SC = 0.18033688f;  // 0.125 * log2(e)
    const uint4 qa4 = *(const uint4*)&qboth[(size_t)node * 128 + t * 8];
    const uint4 qb4 = *(const uint4*)&qboth[(size_t)node * 128 + 64 + t * 8];
    float qa[8], qb[8];
    qa[0] = lo2f(qa4.x) * SC; qa[1] = hi2f(qa4.x) * SC;
    qa[2] = lo2f(qa4.y) * SC; qa[3] = hi2f(qa4.y) * SC;
    qa[4] = lo2f(qa4.z) * SC; qa[5] = hi2f(qa4.z) * SC;
    qa[6] = lo2f(qa4.w) * SC; qa[7] = hi2f(qa4.w) * SC;
    qb[0] = lo2f(qb4.x) * SC; qb[1] = hi2f(qb4.x) * SC;
    qb[2] = lo2f(qb4.y) * SC; qb[3] = hi2f(qb4.y) * SC;
    qb[4] = lo2f(qb4.z) * SC; qb[5] = hi2f(qb4.z) * SC;
    qb[6] = lo2f(qb4.w) * SC; qb[7] = hi2f(qb4.w) * SC;

    const size_t rowbase = (size_t)node * CAP;

    float l0 = 0.0f, l1 = 0.0f;
    float a0[8], a1[8];
#pragma unroll
    for (int i = 0; i < 8; ++i) { a0[i] = 0.0f; a1[i] = 0.0f; }

    for (int j = 0; j < deg; j += 2) {
        const bool v2 = (j + 1) < deg;
        const int s1 = colIdx[rowbase + j];
        const int s2 = colIdx[rowbase + (v2 ? j + 1 : j)];
        const unsigned short* p1 = &kvboth[(size_t)s1 * 256 + t * 8];
        const unsigned short* p2 = &kvboth[(size_t)s2 * 256 + t * 8];
        const uint4 ka1 = *(const uint4*)p1;
        const uint4 va1 = *(const uint4*)(p1 + 64);
        const uint4 kb1 = *(const uint4*)(p1 + 128);
        const uint4 vb1 = *(const uint4*)(p1 + 192);
        const uint4 ka2 = *(const uint4*)p2;
        const uint4 va2 = *(const uint4*)(p2 + 64);
        const uint4 kb2 = *(const uint4*)(p2 + 128);
        const uint4 vb2 = *(const uint4*)(p2 + 192);

        float pa1 = qa[0]*lo2f(ka1.x) + qa[1]*hi2f(ka1.x) + qa[2]*lo2f(ka1.y) + qa[3]*hi2f(ka1.y)
                  + qa[4]*lo2f(ka1.z) + qa[5]*hi2f(ka1.z) + qa[6]*lo2f(ka1.w) + qa[7]*hi2f(ka1.w);
        float pb1 = qb[0]*lo2f(kb1.x) + qb[1]*hi2f(kb1.x) + qb[2]*lo2f(kb1.y) + qb[3]*hi2f(kb1.y)
                  + qb[4]*lo2f(kb1.z) + qb[5]*hi2f(kb1.z) + qb[6]*lo2f(kb1.w) + qb[7]*hi2f(kb1.w);
        float pa2 = qa[0]*lo2f(ka2.x) + qa[1]*hi2f(ka2.x) + qa[2]*lo2f(ka2.y) + qa[3]*hi2f(ka2.y)
                  + qa[4]*lo2f(ka2.z) + qa[5]*hi2f(ka2.z) + qa[6]*lo2f(ka2.w) + qa[7]*hi2f(ka2.w);
        float pb2 = qb[0]*lo2f(kb2.x) + qb[1]*hi2f(kb2.x) + qb[2]*lo2f(kb2.y) + qb[3]*hi2f(kb2.y)
                  + qb[4]*lo2f(kb2.z) + qb[5]*hi2f(kb2.z) + qb[6]*lo2f(kb2.w) + qb[7]*hi2f(kb2.w);
        pa1 += __shfl_xor(pa1, 1); pb1 += __shfl_xor(pb1, 1);
        pa2 += __shfl_xor(pa2, 1); pb2 += __shfl_xor(pb2, 1);
        pa1 += __shfl_xor(pa1, 2); pb1 += __shfl_xor(pb1, 2);
        pa2 += __shfl_xor(pa2, 2); pb2 += __shfl_xor(pb2, 2);
        pa1 += __shfl_xor(pa1, 4); pb1 += __shfl_xor(pb1, 4);
        pa2 += __shfl_xor(pa2, 4); pb2 += __shfl_xor(pb2, 4);

        const float w01 = exp2f(pa1);
        const float w11 = exp2f(pb1);
        const float w02 = v2 ? exp2f(pa2) : 0.0f;
        const float w12 = v2 ? exp2f(pb2) : 0.0f;
        l0 += w01 + w02; l1 += w11 + w12;

        a0[0] += w01*lo2f(va1.x) + w02*lo2f(va2.x);
        a0[1] += w01*hi2f(va1.x) + w02*hi2f(va2.x);
        a0[2] += w01*lo2f(va1.y) + w02*lo2f(va2.y);
        a0[3] += w01*hi2f(va1.y) + w02*hi2f(va2.y);
        a0[4] += w01*lo2f(va1.z) + w02*lo2f(va2.z);
        a0[5] += w01*hi2f(va1.z) + w02*hi2f(va2.z);
        a0[6] += w01*lo2f(va1.w) + w02*lo2f(va2.w);
        a0[7] += w01*hi2f(va1.w) + w02*hi2f(va2.w);
        a1[0] += w11*lo2f(vb1.x) + w12*lo2f(vb2.x);
        a1[1] += w11*hi2f(vb1.x) + w12*hi2f(vb2.x);
        a1[2] += w11*lo2f(vb1.y) + w12*lo2f(vb2.y);
        a1[3] += w11*hi2f(vb1.y) + w12*hi2f(vb2.y);
        a1[4] += w11*lo2f(vb1.z) + w12*lo2f(vb2.z);
        a1[5] += w11*hi2f(vb1.z) + w12*hi2f(vb2.z);
        a1[6] += w11*lo2f(vb1.w) + w12*lo2f(vb2.w);
        a1[7] += w11*hi2f(vb1.w) + w12*hi2f(vb2.w);
    }

    const float inv0 = 1.0f / (l0 + 1e-16f);
    const float inv1 = 1.0f / (l1 + 1e-16f);
    float* pout = &tgt[(size_t)node * 64 + t * 8];
    float4 o1 = *(float4*)pout;
    float4 o2 = *(float4*)(pout + 4);
    o1.x += a0[0] * inv0 + a1[0] * inv1;
    o1.y += a0[1] * inv0 + a1[1] * inv1;
    o1.z += a0[2] * inv0 + a1[2] * inv1;
    o1.w += a0[3] * inv0 + a1[3] * inv1;
    o2.x += a0[4] * inv0 + a1[4] * inv1;
    o2.y += a0[5] * inv0 + a1[5] * inv1;
    o2.z += a0[6] * inv0 + a1[6] * inv1;
    o2.w += a0[7] * inv0 + a1[7] * inv1;
    *(float4*)pout = o1;
    *(float4*)(pout + 4) = o2;
}

// ---------------- elementwise (vectorized x4) ----------------

__global__ void rh_kernel(const float* __restrict__ rpre, const float* __restrict__ h,
                          unsigned short* __restrict__ rhb, int n) {
    int i = (blockIdx.x * 256 + threadIdx.x) * 4;
    if (i < n) {
        float4 rp = *(const float4*)&rpre[i];
        float4 hh = *(const float4*)&h[i];
        ushort4 o;
        o.x = f2bf(hh.x / (1.0f + __expf(-rp.x)));
        o.y = f2bf(hh.y / (1.0f + __expf(-rp.y)));
        o.z = f2bf(hh.z / (1.0f + __expf(-rp.z)));
        o.w = f2bf(hh.w / (1.0f + __expf(-rp.w)));
        *(ushort4*)&rhb[i] = o;
    }
}

__global__ void final_kernel(const float* __restrict__ zpre, const float* __restrict__ h,
                             const float* __restrict__ c45, float* __restrict__ out, int n) {
    int i = (blockIdx.x * 256 + threadIdx.x) * 4;
    if (i < n) {
        float4 zp = *(const float4*)&zpre[i];
        float4 hh = *(const float4*)&h[i];
        float4 cc = *(const float4*)&c45[i];
        float4 r;
        float z0 = 1.0f / (1.0f + __expf(-zp.x));
        float z1 = 1.0f / (1.0f + __expf(-zp.y));
        float z2 = 1.0f / (1.0f + __expf(-zp.z));
        float z3 = 1.0f / (1.0f + __expf(-zp.w));
        r.x = z0 * hh.x + (1.0f - z0) * tanhf(cc.x);
        r.y = z1 * hh.y + (1.0f - z1) * tanhf(cc.y);
        r.z = z2 * hh.z + (1.0f - z2) * tanhf(cc.z);
        r.w = z3 * hh.w + (1.0f - z3) * tanhf(cc.w);
        *(float4*)&out[i] = r;
    }
}

// ---------------- launch ----------------

extern "C" void kernel_launch(void* const* d_in, const int* in_sizes, int n_in,
                              void* d_out, int out_size, void* d_ws, size_t ws_size,
                              hipStream_t stream) {
    const int N = N_NODES, E = N_EDGES;
    const float* x  = (const float*)d_in[0];
    const float* h  = (const float*)d_in[1];
    const int*  ei  = (const int*)d_in[2];
    const float* Wq = (const float*)d_in[3];
    const float* bq = (const float*)d_in[4];
    const float* Wk = (const float*)d_in[5];
    const float* bk = (const float*)d_in[6];
    const float* Wv = (const float*)d_in[7];
    const float* bv = (const float*)d_in[8];
    const float* Ws = (const float*)d_in[9];
    const float* bs = (const float*)d_in[10];
    float* out = (float*)d_out;

    const int* src = ei;
    const int* dst = ei + E;

    // ---- workspace layout ----
    char* w = (char*)d_ws;
    int* cnt    = (int*)w;                        // N
    int* colIdx = cnt + N;                        // N*CAP
    size_t intWords = (size_t)N + (size_t)N * CAP;
    char* p = w + ((intWords * 4 + 255) & ~(size_t)255);

    const size_t ND = (size_t)N * D;
    float* zpre = (float*)p;            p += ND * 4;
    float* rpre = (float*)p;            p += ND * 4;
    float* c45  = (float*)p;            p += ND * 4;
    float* ball = (float*)p;            p += N_CONVS * 256 * 4;
    unsigned short* xb     = (unsigned short*)p; p += ND * 2;
    unsigned short* hb     = (unsigned short*)p; p += ND * 2;
    unsigned short* rhb    = (unsigned short*)p; p += ND * 2;
    unsigned short* qboth  = (unsigned short*)p; p += ND * 2 * 2;   // [N][128]
    unsigned short* kvboth = (unsigned short*)p; p += ND * 2 * 4;   // [N][256]
    unsigned short* WT     = (unsigned short*)p; p += (size_t)N_CONVS * 256 * 64 * 2;

    const int NB_CVT = (int)(ND / 4 / 256);             // 6250 (exact)
    const int NB_PP = (N_CONVS * 256 * 64 + 255) / 256; // 384
    const int NB_GEMM = (N + 63) / 64;                  // 1563
    const int NB_E4 = (E / 4 + 255) / 256;              // 977
    const int NB_ATTN = (N + 31) / 32;                  // 3125
    const int NB_EW = (int)(ND / 4 / 256);              // 6250

    prep_all<<<NB_CVT + NB_PP, 256, 0, stream>>>(x, h, xb, hb, Wq, Wk, Wv, Ws,
                                                 bq, bk, bv, bs, WT, ball, NB_CVT);
    hipMemsetAsync(cnt, 0, (size_t)N * sizeof(int), stream);
    fill_cap<<<NB_E4, 256, 0, stream>>>(src, dst, E, cnt, colIdx);

#define WTc(i) (WT + (size_t)(i) * 256 * 64)
#define BLc(i) (ball + (size_t)(i) * 256)

    // pair (0,1) -> zpre
    gemm_pair<<<NB_GEMM, 512, 0, stream>>>(
        xb, hb, N, WTc(0), WTc(1), BLc(0), BLc(1), qboth, kvboth, zpre);
    edge_attn2<<<NB_ATTN, 256, 0, stream>>>(cnt, colIdx, qboth, kvboth, zpre, N);

    // pair (2,3) -> rpre
    gemm_pair<<<NB_GEMM, 512, 0, stream>>>(
        xb, hb, N, WTc(2), WTc(3), BLc(2), BLc(3), qboth, kvboth, rpre);
    edge_attn2<<<NB_ATTN, 256, 0, stream>>>(cnt, colIdx, qboth, kvboth, rpre, N);

    // rh, then pair (4,5) -> c45
    rh_kernel<<<NB_EW, 256, 0, stream>>>(rpre, h, rhb, (int)ND);
    gemm_pair<<<NB_GEMM, 512, 0, stream>>>(
        xb, rhb, N, WTc(4), WTc(5), BLc(4), BLc(5), qboth, kvboth, c45);
    edge_attn2<<<NB_ATTN, 256, 0, stream>>>(cnt, colIdx, qboth, kvboth, c45, N);

    final_kernel<<<NB_EW, 256, 0, stream>>>(zpre, h, c45, out, (int)ND);

#undef WTc
#undef BLc
}

// Round 9
// 398.738 us; speedup vs baseline: 1.2883x; 1.2570x over previous
//
#include <hip/hip_runtime.h>
#include <math.h>

#define N_NODES 100000
#define N_EDGES 1000000
#define D 64
#define N_CONVS 6
#define CAP 64  // max degree bucket (Poisson(10): P(deg>64) ~ 1e-30/node)
#define NDTOT (N_NODES * D)

typedef __bf16 bf16x8 __attribute__((ext_vector_type(8)));
typedef float f32x4 __attribute__((ext_vector_type(4)));
typedef float f32x2 __attribute__((ext_vector_type(2)));

static __device__ __forceinline__ float hi2f(unsigned int d) {
    union { unsigned int i; float f; } c; c.i = d & 0xFFFF0000u; return c.f;
}
static __device__ __forceinline__ float lo2f(unsigned int d) {
    union { unsigned int i; float f; } c; c.i = d << 16; return c.f;
}
static __device__ __forceinline__ unsigned short f2bf(float f) {
    union { float f; unsigned int i; } c; c.f = f;
    unsigned int x = c.i;
    unsigned int r = (x + 0x7fffu + ((x >> 16) & 1u)) >> 16;
    return (unsigned short)r;
}

// ---------------- fp8 e4m3 helpers (HW cvt on gfx950; software fallback) ----------------

#if __has_builtin(__builtin_amdgcn_cvt_pk_f32_fp8) && __has_builtin(__builtin_amdgcn_cvt_pk_fp8_f32)
#define HW_FP8 1
#endif

#ifndef HW_FP8
static __device__ __forceinline__ float dec1(unsigned int b) {
    union { unsigned int i; float f; } c;
    c.i = ((b & 0x80u) << 24) | ((b & 0x7fu) << 20);
    return c.f * 0x1p+120f;
}
static __device__ __forceinline__ unsigned int enc1(float f) {
    union { float f; unsigned int i; } c; c.f = f;
    unsigned int s = (c.i >> 24) & 0x80u;
    float a = fabsf(f);
    a = fminf(a, 448.0f);
    c.f = a * 0x1p-120f;
    unsigned int u = c.i;
    unsigned int bits = (u + 0x7FFFFu + ((u >> 20) & 1u)) >> 20;
    if (bits > 0x7Eu) bits = 0x7Eu;
    return s | bits;
}
#endif

static __device__ __forceinline__ void dec8(unsigned int lo, unsigned int hi, float* f) {
#ifdef HW_FP8
    f32x2 p0 = __builtin_amdgcn_cvt_pk_f32_fp8(lo, false);
    f32x2 p1 = __builtin_amdgcn_cvt_pk_f32_fp8(lo, true);
    f32x2 p2 = __builtin_amdgcn_cvt_pk_f32_fp8(hi, false);
    f32x2 p3 = __builtin_amdgcn_cvt_pk_f32_fp8(hi, true);
    f[0] = p0[0]; f[1] = p0[1]; f[2] = p1[0]; f[3] = p1[1];
    f[4] = p2[0]; f[5] = p2[1]; f[6] = p3[0]; f[7] = p3[1];
#else
#pragma unroll
    for (int i = 0; i < 4; ++i) f[i] = dec1((lo >> (8 * i)) & 0xFFu);
#pragma unroll
    for (int i = 0; i < 4; ++i) f[4 + i] = dec1((hi >> (8 * i)) & 0xFFu);
#endif
}

static __device__ __forceinline__ unsigned int enc4(float a, float b, float c2, float d) {
#ifdef HW_FP8
    int r = 0;
    r = __builtin_amdgcn_cvt_pk_fp8_f32(a, b, r, false);
    r = __builtin_amdgcn_cvt_pk_fp8_f32(c2, d, r, true);
    return (unsigned int)r;
#else
    return enc1(a) | (enc1(b) << 8) | (enc1(c2) << 16) | (enc1(d) << 24);
#endif
}

// ---------------- bucket-CSR build: 4 edges/thread for MLP ----------------

__global__ void fill_cap(const int* __restrict__ src, const int* __restrict__ dst, int E,
                         int* __restrict__ cnt, int* __restrict__ colIdx) {
    int e0 = (blockIdx.x * 256 + threadIdx.x) * 4;
    if (e0 + 3 < E) {
        const int4 d4 = *(const int4*)&dst[e0];
        const int4 s4 = *(const int4*)&src[e0];
        int t0 = atomicAdd(&cnt[d4.x], 1);
        int t1 = atomicAdd(&cnt[d4.y], 1);
        int t2 = atomicAdd(&cnt[d4.z], 1);
        int t3 = atomicAdd(&cnt[d4.w], 1);
        if (t0 < CAP) colIdx[(size_t)d4.x * CAP + t0] = s4.x;
        if (t1 < CAP) colIdx[(size_t)d4.y * CAP + t1] = s4.y;
        if (t2 < CAP) colIdx[(size_t)d4.z * CAP + t2] = s4.z;
        if (t3 < CAP) colIdx[(size_t)d4.w * CAP + t3] = s4.w;
    } else {
        for (int e = e0; e < E; ++e) {
            int d = dst[e];
            int slot = atomicAdd(&cnt[d], 1);
            if (slot < CAP) colIdx[(size_t)d * CAP + slot] = src[e];
        }
    }
}

// ---------------- prep: fp32->bf16 converts + weight prepack, one launch ----------------

__global__ void prep_all(const float* __restrict__ x, const float* __restrict__ h,
                         unsigned short* __restrict__ xb, unsigned short* __restrict__ hb,
                         const float* __restrict__ Wq, const float* __restrict__ Wk,
                         const float* __restrict__ Wv, const float* __restrict__ Ws,
                         const float* __restrict__ bq, const float* __restrict__ bk,
                         const float* __restrict__ bv, const float* __restrict__ bs,
                         unsigned short* __restrict__ WT, float* __restrict__ ball,
                         int nCvt) {
    int b = blockIdx.x;
    if (b < nCvt) {
        int i = (b * 256 + threadIdx.x) * 4;
        if (i < NDTOT) {
            float4 fx = *(const float4*)&x[i];
            float4 fh = *(const float4*)&h[i];
            ushort4 ux, uh;
            ux.x = f2bf(fx.x); ux.y = f2bf(fx.y); ux.z = f2bf(fx.z); ux.w = f2bf(fx.w);
            uh.x = f2bf(fh.x); uh.y = f2bf(fh.y); uh.z = f2bf(fh.z); uh.w = f2bf(fh.w);
            *(ushort4*)&xb[i] = ux;
            *(ushort4*)&hb[i] = uh;
        }
    } else {
        int idx = (b - nCvt) * 256 + threadIdx.x;   // conv*16384 + n*64 + k
        if (idx >= N_CONVS * 256 * 64) return;
        int conv = idx >> 14;
        int rem = idx & 16383;
        int n = rem >> 6, kk = rem & 63;
        int mat = n >> 6, c = n & 63;
        const float* W = mat == 0 ? Wq : mat == 1 ? Wk : mat == 2 ? Wv : Ws;
        WT[idx] = f2bf(W[conv * 4096 + kk * 64 + c]);
        if (kk == 0) {
            const float* B = mat == 0 ? bq : mat == 1 ? bk : mat == 2 ? bv : bs;
            ball[conv * 256 + n] = B[conv * 64 + c];
        }
    }
}

// ---------------- pair GEMM: convA(XA) & convB(XB), swapped-operand MFMA ----------------
// 512 threads = 8 waves. wave = conv*4 + mat; mat 0..2 -> q/k/v, mat 3 -> skip.
// q -> qboth[node][128] bf16 (qA|qB); k,v -> kv8[node][256] fp8 (kA|vA|kB|vB).

static __device__ __forceinline__ void gemm_pair_body(
    const unsigned short* __restrict__ XA, const unsigned short* __restrict__ XB, int N,
    const unsigned short* __restrict__ WTA, const unsigned short* __restrict__ WTB,
    const float* __restrict__ ballA, const float* __restrict__ ballB,
    unsigned short* __restrict__ qboth, unsigned char* __restrict__ kv8,
    float* __restrict__ sk)
{
    __shared__ __align__(16) unsigned short XLA[64][72];
    __shared__ __align__(16) unsigned short XLB[64][72];
    __shared__ __align__(16) float SKIP[64][68];

    const int tid = threadIdx.x;
    const int base = blockIdx.x * 64;
    const int lane = tid & 63;
    const int wave = tid >> 6;
    const int conv = wave >> 2;
    const int mat = wave & 3;

    {
        int r = tid >> 3, cc = (tid & 7) * 8;
        uint4 va = {0u,0u,0u,0u}, vb = {0u,0u,0u,0u};
        if (base + r < N) {
            va = *(const uint4*)&XA[(size_t)(base + r) * D + cc];
            vb = *(const uint4*)&XB[(size_t)(base + r) * D + cc];
        }
        *(uint4*)&XLA[r][cc] = va;
        *(uint4*)&XLB[r][cc] = vb;
    }
    __syncthreads();

    const int l15 = lane & 15;
    const int lhi = lane >> 4;
    const int n0 = mat * 64;
    const unsigned short* WT = conv ? WTB : WTA;
    const float* ball = conv ? ballB : ballA;

    bf16x8 Wf[4][2];
#pragma unroll
    for (int ni = 0; ni < 4; ++ni)
#pragma unroll
        for (int ks = 0; ks < 2; ++ks)
            Wf[ni][ks] = *(const bf16x8*)&WT[(size_t)(n0 + ni * 16 + l15) * D + lhi * 8 + ks * 32];

    bf16x8 Xf[4][2];
#pragma unroll
    for (int mi = 0; mi < 4; ++mi)
#pragma unroll
        for (int ks = 0; ks < 2; ++ks)
            Xf[mi][ks] = conv ? *(const bf16x8*)&XLB[mi * 16 + l15][lhi * 8 + ks * 32]
                              : *(const bf16x8*)&XLA[mi * 16 + l15][lhi * 8 + ks * 32];

    f32x4 acc[4][4];
#pragma unroll
    for (int ni = 0; ni < 4; ++ni) {
        const float4 b4 = *(const float4*)&ball[n0 + ni * 16 + lhi * 4];
#pragma unroll
        for (int mi = 0; mi < 4; ++mi) {
            f32x4 t;
            t[0] = b4.x; t[1] = b4.y; t[2] = b4.z; t[3] = b4.w;
            acc[mi][ni] = t;
        }
    }

#pragma unroll
    for (int ks = 0; ks < 2; ++ks)
#pragma unroll
        for (int mi = 0; mi < 4; ++mi)
#pragma unroll
            for (int ni = 0; ni < 4; ++ni)
                acc[mi][ni] = __builtin_amdgcn_mfma_f32_16x16x32_bf16(
                    Wf[ni][ks], Xf[mi][ks], acc[mi][ni], 0, 0, 0);

    if (mat == 0) {
        // q -> qboth[row*128 + conv*64 + col] (bf16)
        unsigned short* outb = qboth + conv * 64;
#pragma unroll
        for (int mi = 0; mi < 4; ++mi) {
            int row = base + mi * 16 + l15;
            if (row < N) {
#pragma unroll
                for (int ni = 0; ni < 4; ++ni) {
                    int col = ni * 16 + lhi * 4;
                    ushort4 u;
                    u.x = f2bf(acc[mi][ni][0]); u.y = f2bf(acc[mi][ni][1]);
                    u.z = f2bf(acc[mi][ni][2]); u.w = f2bf(acc[mi][ni][3]);
                    *(ushort4*)&outb[(size_t)row * 128 + col] = u;
                }
            }
        }
    } else if (mat < 3) {
        // k -> kv8[row*256 + conv*128 + col]; v -> +64  (fp8 e4m3)
        unsigned char* outb = kv8 + conv * 128 + (mat == 2 ? 64 : 0);
#pragma unroll
        for (int mi = 0; mi < 4; ++mi) {
            int row = base + mi * 16 + l15;
            if (row < N) {
#pragma unroll
                for (int ni = 0; ni < 4; ++ni) {
                    int col = ni * 16 + lhi * 4;
                    unsigned int r = enc4(acc[mi][ni][0], acc[mi][ni][1],
                                          acc[mi][ni][2], acc[mi][ni][3]);
                    *(unsigned int*)&outb[(size_t)row * 256 + col] = r;
                }
            }
        }
    } else if (conv == 0) {
#pragma unroll
        for (int mi = 0; mi < 4; ++mi)
#pragma unroll
            for (int ni = 0; ni < 4; ++ni)
                *(f32x4*)&SKIP[mi * 16 + l15][ni * 16 + lhi * 4] = acc[mi][ni];
    }
    __syncthreads();
    if (mat == 3 && conv == 1) {
#pragma unroll
        for (int mi = 0; mi < 4; ++mi) {
            int row = base + mi * 16 + l15;
            if (row < N) {
#pragma unroll
                for (int ni = 0; ni < 4; ++ni) {
                    int col = ni * 16 + lhi * 4;
                    const f32x4 s4 = *(const f32x4*)&SKIP[mi * 16 + l15][col];
                    float4 r4;
                    r4.x = acc[mi][ni][0] + s4[0];
                    r4.y = acc[mi][ni][1] + s4[1];
                    r4.z = acc[mi][ni][2] + s4[2];
                    r4.w = acc[mi][ni][3] + s4[3];
                    *(float4*)&sk[(size_t)row * 64 + col] = r4;
                }
            }
        }
    }
}

__global__ __launch_bounds__(512) void gemm_pair(
    const unsigned short* __restrict__ XA, const unsigned short* __restrict__ XB, int N,
    const unsigned short* __restrict__ WTA, const unsigned short* __restrict__ WTB,
    const float* __restrict__ ballA, const float* __restrict__ ballB,
    unsigned short* __restrict__ qboth, unsigned char* __restrict__ kv8,
    float* __restrict__ sk)
{
    gemm_pair_body(XA, XB, N, WTA, WTB, ballA, ballB, qboth, kv8, sk);
}

// ---------------- dual-conv edge attention: 8-lane group per node, fp8 kv ----------------
// Per edge the group reads one CONTIGUOUS 256B fp8 block (k0|v0|k1|v1), 2 edges/iter.
// Dot reduce = 3 intra-group shfls. No-max softmax: scores bounded, exp2 safe.

__global__ __launch_bounds__(256) void edge_attn2(
    const int* __restrict__ cnt, const int* __restrict__ colIdx,
    const unsigned short* __restrict__ qboth, const unsigned char* __restrict__ kv8,
    float* __restrict__ tgt, int N)
{
    const int tid = threadIdx.x;
    const int node = blockIdx.x * 32 + (tid >> 3);
    if (node >= N) return;
    const int t = tid & 7;

    int deg = cnt[node];
    if (deg > CAP) deg = CAP;

    const float SC = 0.18033688f;  // 0.125 * log2(e)
    const uint4 qa4 = *(const uint4*)&qboth[(size_t)node * 128 + t * 8];
    const uint4 qb4 = *(const uint4*)&qboth[(size_t)node * 128 + 64 + t * 8];
    float qa[8], qb[8];
    qa[0] = lo2f(qa4.x) * SC; qa[1] = hi2f(qa4.x) * SC;
    qa[2] = lo2f(qa4.y) * SC; qa[3] = hi2f(qa4.y) * SC;
    qa[4] = lo2f(qa4.z) * SC; qa[5] = hi2f(qa4.z) * SC;
    qa[6] = lo2f(qa4.w) * SC; qa[7] = hi2f(qa4.w) * SC;
    qb[0] = lo2f(qb4.x) * SC; qb[1] = hi2f(qb4.x) * SC;
    qb[2] = lo2f(qb4.y) * SC; qb[3] = hi2f(qb4.y) * SC;
    qb[4] = lo2f(qb4.z) * SC; qb[5] = hi2f(qb4.z) * SC;
    qb[6] = lo2f(qb4.w) * SC; qb[7] = hi2f(qb4.w) * SC;

    const size_t rowbase = (size_t)node * CAP;

    float l0 = 0.0f, l1 = 0.0f;
    float a0[8], a1[8];
#pragma unroll
    for (int i = 0; i < 8; ++i) { a0[i] = 0.0f; a1[i] = 0.0f; }

    for (int j = 0; j < deg; j += 2) {
        const bool v2 = (j + 1) < deg;
        const int s1 = colIdx[rowbase + j];
        const int s2 = colIdx[rowbase + (v2 ? j + 1 : j)];
        const unsigned char* p1 = kv8 + (size_t)s1 * 256 + t * 8;
        const unsigned char* p2 = kv8 + (size_t)s2 * 256 + t * 8;
        const uint2 ka1 = *(const uint2*)p1;
        const uint2 va1 = *(const uint2*)(p1 + 64);
        const uint2 kb1 = *(const uint2*)(p1 + 128);
        const uint2 vb1 = *(const uint2*)(p1 + 192);
        const uint2 ka2 = *(const uint2*)p2;
        const uint2 va2 = *(const uint2*)(p2 + 64);
        const uint2 kb2 = *(const uint2*)(p2 + 128);
        const uint2 vb2 = *(const uint2*)(p2 + 192);

        float kf[8];
        dec8(ka1.x, ka1.y, kf);
        float pa1 = qa[0]*kf[0] + qa[1]*kf[1] + qa[2]*kf[2] + qa[3]*kf[3]
                  + qa[4]*kf[4] + qa[5]*kf[5] + qa[6]*kf[6] + qa[7]*kf[7];
        dec8(kb1.x, kb1.y, kf);
        float pb1 = qb[0]*kf[0] + qb[1]*kf[1] + qb[2]*kf[2] + qb[3]*kf[3]
                  + qb[4]*kf[4] + qb[5]*kf[5] + qb[6]*kf[6] + qb[7]*kf[7];
        dec8(ka2.x, ka2.y, kf);
        float pa2 = qa[0]*kf[0] + qa[1]*kf[1] + qa[2]*kf[2] + qa[3]*kf[3]
                  + qa[4]*kf[4] + qa[5]*kf[5] + qa[6]*kf[6] + qa[7]*kf[7];
        dec8(kb2.x, kb2.y, kf);
        float pb2 = qb[0]*kf[0] + qb[1]*kf[1] + qb[2]*kf[2] + qb[3]*kf[3]
                  + qb[4]*kf[4] + qb[5]*kf[5] + qb[6]*kf[6] + qb[7]*kf[7];

        pa1 += __shfl_xor(pa1, 1); pb1 += __shfl_xor(pb1, 1);
        pa2 += __shfl_xor(pa2, 1); pb2 += __shfl_xor(pb2, 1);
        pa1 += __shfl_xor(pa1, 2); pb1 += __shfl_xor(pb1, 2);
        pa2 += __shfl_xor(pa2, 2); pb2 += __shfl_xor(pb2, 2);
        pa1 += __shfl_xor(pa1, 4); pb1 += __shfl_xor(pb1, 4);
        pa2 += __shfl_xor(pa2, 4); pb2 += __shfl_xor(pb2, 4);

        const float w01 = exp2f(pa1);
        const float w11 = exp2f(pb1);
        const float w02 = v2 ? exp2f(pa2) : 0.0f;
        const float w12 = v2 ? exp2f(pb2) : 0.0f;
        l0 += w01 + w02; l1 += w11 + w12;

        float vf1[8], vf2[8];
        dec8(va1.x, va1.y, vf1);
        dec8(va2.x, va2.y, vf2);
#pragma unroll
        for (int i = 0; i < 8; ++i) a0[i] += w01 * vf1[i] + w02 * vf2[i];
        dec8(vb1.x, vb1.y, vf1);
        dec8(vb2.x, vb2.y, vf2);
#pragma unroll
        for (int i = 0; i < 8; ++i) a1[i] += w11 * vf1[i] + w12 * vf2[i];
    }

    const float inv0 = 1.0f / (l0 + 1e-16f);
    const float inv1 = 1.0f / (l1 + 1e-16f);
    float* pout = &tgt[(size_t)node * 64 + t * 8];
    float4 o1 = *(float4*)pout;
    float4 o2 = *(float4*)(pout + 4);
    o1.x += a0[0] * inv0 + a1[0] * inv1;
    o1.y += a0[1] * inv0 + a1[1] * inv1;
    o1.z += a0[2] * inv0 + a1[2] * inv1;
    o1.w += a0[3] * inv0 + a1[3] * inv1;
    o2.x += a0[4] * inv0 + a1[4] * inv1;
    o2.y += a0[5] * inv0 + a1[5] * inv1;
    o2.z += a0[6] * inv0 + a1[6] * inv1;
    o2.w += a0[7] * inv0 + a1[7] * inv1;
    *(float4*)pout = o1;
    *(float4*)(pout + 4) = o2;
}

// ---------------- elementwise (vectorized x4) ----------------

__global__ void rh_kernel(const float* __restrict__ rpre, const float* __restrict__ h,
                          unsigned short* __restrict__ rhb, int n) {
    int i = (blockIdx.x * 256 + threadIdx.x) * 4;
    if (i < n) {
        float4 rp = *(const float4*)&rpre[i];
        float4 hh = *(const float4*)&h[i];
        ushort4 o;
        o.x = f2bf(hh.x / (1.0f + __expf(-rp.x)));
        o.y = f2bf(hh.y / (1.0f + __expf(-rp.y)));
        o.z = f2bf(hh.z / (1.0f + __expf(-rp.z)));
        o.w = f2bf(hh.w / (1.0f + __expf(-rp.w)));
        *(ushort4*)&rhb[i] = o;
    }
}

__global__ void final_kernel(const float* __restrict__ zpre, const float* __restrict__ h,
                             const float* __restrict__ c45, float* __restrict__ out, int n) {
    int i = (blockIdx.x * 256 + threadIdx.x) * 4;
    if (i < n) {
        float4 zp = *(const float4*)&zpre[i];
        float4 hh = *(const float4*)&h[i];
        float4 cc = *(const float4*)&c45[i];
        float4 r;
        float z0 = 1.0f / (1.0f + __expf(-zp.x));
        float z1 = 1.0f / (1.0f + __expf(-zp.y));
        float z2 = 1.0f / (1.0f + __expf(-zp.z));
        float z3 = 1.0f / (1.0f + __expf(-zp.w));
        r.x = z0 * hh.x + (1.0f - z0) * tanhf(cc.x);
        r.y = z1 * hh.y + (1.0f - z1) * tanhf(cc.y);
        r.z = z2 * hh.z + (1.0f - z2) * tanhf(cc.z);
        r.w = z3 * hh.w + (1.0f - z3) * tanhf(cc.w);
        *(float4*)&out[i] = r;
    }
}

// ---------------- launch ----------------

extern "C" void kernel_launch(void* const* d_in, const int* in_sizes, int n_in,
                              void* d_out, int out_size, void* d_ws, size_t ws_size,
                              hipStream_t stream) {
    const int N = N_NODES, E = N_EDGES;
    const float* x  = (const float*)d_in[0];
    const float* h  = (const float*)d_in[1];
    const int*  ei  = (const int*)d_in[2];
    const float* Wq = (const float*)d_in[3];
    const float* bq = (const float*)d_in[4];
    const float* Wk = (const float*)d_in[5];
    const float* bk = (const float*)d_in[6];
    const float* Wv = (const float*)d_in[7];
    const float* bv = (const float*)d_in[8];
    const float* Ws = (const float*)d_in[9];
    const float* bs = (const float*)d_in[10];
    float* out = (float*)d_out;

    const int* src = ei;
    const int* dst = ei + E;

    // ---- workspace layout ----
    char* w = (char*)d_ws;
    int* cnt    = (int*)w;                        // N
    int* colIdx = cnt + N;                        // N*CAP
    size_t intWords = (size_t)N + (size_t)N * CAP;
    char* p = w + ((intWords * 4 + 255) & ~(size_t)255);

    const size_t ND = (size_t)N * D;
    float* zpre = (float*)p;            p += ND * 4;
    float* rpre = (float*)p;            p += ND * 4;
    float* c45  = (float*)p;            p += ND * 4;
    float* ball = (float*)p;            p += N_CONVS * 256 * 4;
    unsigned short* xb    = (unsigned short*)p; p += ND * 2;
    unsigned short* hb    = (unsigned short*)p; p += ND * 2;
    unsigned short* rhb   = (unsigned short*)p; p += ND * 2;
    unsigned short* qboth = (unsigned short*)p; p += ND * 2 * 2;   // [N][128] bf16
    unsigned char*  kv8   = (unsigned char*)p;  p += (size_t)N_NODES * 256;  // [N][256] fp8
    unsigned short* WT    = (unsigned short*)p; p += (size_t)N_CONVS * 256 * 64 * 2;

    const int NB_CVT = (int)(ND / 4 / 256);             // 6250 (exact)
    const int NB_PP = (N_CONVS * 256 * 64 + 255) / 256; // 384
    const int NB_GEMM = (N + 63) / 64;                  // 1563
    const int NB_E4 = (E / 4 + 255) / 256;              // 977
    const int NB_ATTN = (N + 31) / 32;                  // 3125
    const int NB_EW = (int)(ND / 4 / 256);              // 6250

    prep_all<<<NB_CVT + NB_PP, 256, 0, stream>>>(x, h, xb, hb, Wq, Wk, Wv, Ws,
                                                 bq, bk, bv, bs, WT, ball, NB_CVT);
    hipMemsetAsync(cnt, 0, (size_t)N * sizeof(int), stream);
    fill_cap<<<NB_E4, 256, 0, stream>>>(src, dst, E, cnt, colIdx);

#define WTc(i) (WT + (size_t)(i) * 256 * 64)
#define BLc(i) (ball + (size_t)(i) * 256)

    // pair (0,1) -> zpre
    gemm_pair<<<NB_GEMM, 512, 0, stream>>>(
        xb, hb, N, WTc(0), WTc(1), BLc(0), BLc(1), qboth, kv8, zpre);
    edge_attn2<<<NB_ATTN, 256, 0, stream>>>(cnt, colIdx, qboth, kv8, zpre, N);

    // pair (2,3) -> rpre
    gemm_pair<<<NB_GEMM, 512, 0, stream>>>(
        xb, hb, N, WTc(2), WTc(3), BLc(2), BLc(3), qboth, kv8, rpre);
    edge_attn2<<<NB_ATTN, 256, 0, stream>>>(cnt, colIdx, qboth, kv8, rpre, N);

    // rh, then pair (4,5) -> c45
    rh_kernel<<<NB_EW, 256, 0, stream>>>(rpre, h, rhb, (int)ND);
    gemm_pair<<<NB_GEMM, 512, 0, stream>>>(
        xb, rhb, N, WTc(4), WTc(5), BLc(4), BLc(5), qboth, kv8, c45);
    edge_attn2<<<NB_ATTN, 256, 0, stream>>>(cnt, colIdx, qboth, kv8, c45, N);

    final_kernel<<<NB_EW, 256, 0, stream>>>(zpre, h, c45, out, (int)ND);

#undef WTc
#undef BLc
}

// Round 10
// 375.874 us; speedup vs baseline: 1.3667x; 1.0608x over previous
//
#include <hip/hip_runtime.h>
#include <math.h>

#define N_NODES 100000
#define N_EDGES 1000000
#define D 64
#define N_CONVS 6
#define CAP 64  // max degree bucket (Poisson(10): P(deg>64) ~ 1e-30/node)
#define NDTOT (N_NODES * D)
#define NPART 8           // = XCD count; N_NODES/NPART = 12500 exact
#define CHUNK 4096        // edges per chunk-block

typedef __bf16 bf16x8 __attribute__((ext_vector_type(8)));
typedef float f32x4 __attribute__((ext_vector_type(4)));
typedef float f32x2 __attribute__((ext_vector_type(2)));

static __device__ __forceinline__ float hi2f(unsigned int d) {
    union { unsigned int i; float f; } c; c.i = d & 0xFFFF0000u; return c.f;
}
static __device__ __forceinline__ float lo2f(unsigned int d) {
    union { unsigned int i; float f; } c; c.i = d << 16; return c.f;
}
static __device__ __forceinline__ unsigned short f2bf(float f) {
    union { float f; unsigned int i; } c; c.f = f;
    unsigned int x = c.i;
    unsigned int r = (x + 0x7fffu + ((x >> 16) & 1u)) >> 16;
    return (unsigned short)r;
}

// ---------------- fp8 e4m3 helpers (HW cvt on gfx950; software fallback) ----------------

#if __has_builtin(__builtin_amdgcn_cvt_pk_f32_fp8) && __has_builtin(__builtin_amdgcn_cvt_pk_fp8_f32)
#define HW_FP8 1
#endif

#ifndef HW_FP8
static __device__ __forceinline__ float dec1(unsigned int b) {
    union { unsigned int i; float f; } c;
    c.i = ((b & 0x80u) << 24) | ((b & 0x7fu) << 20);
    return c.f * 0x1p+120f;
}
static __device__ __forceinline__ unsigned int enc1(float f) {
    union { float f; unsigned int i; } c; c.f = f;
    unsigned int s = (c.i >> 24) & 0x80u;
    float a = fabsf(f);
    a = fminf(a, 448.0f);
    c.f = a * 0x1p-120f;
    unsigned int u = c.i;
    unsigned int bits = (u + 0x7FFFFu + ((u >> 20) & 1u)) >> 20;
    if (bits > 0x7Eu) bits = 0x7Eu;
    return s | bits;
}
#endif

static __device__ __forceinline__ void dec8(unsigned int lo, unsigned int hi, float* f) {
#ifdef HW_FP8
    f32x2 p0 = __builtin_amdgcn_cvt_pk_f32_fp8(lo, false);
    f32x2 p1 = __builtin_amdgcn_cvt_pk_f32_fp8(lo, true);
    f32x2 p2 = __builtin_amdgcn_cvt_pk_f32_fp8(hi, false);
    f32x2 p3 = __builtin_amdgcn_cvt_pk_f32_fp8(hi, true);
    f[0] = p0[0]; f[1] = p0[1]; f[2] = p1[0]; f[3] = p1[1];
    f[4] = p2[0]; f[5] = p2[1]; f[6] = p3[0]; f[7] = p3[1];
#else
#pragma unroll
    for (int i = 0; i < 4; ++i) f[i] = dec1((lo >> (8 * i)) & 0xFFu);
#pragma unroll
    for (int i = 0; i < 4; ++i) f[4 + i] = dec1((hi >> (8 * i)) & 0xFFu);
#endif
}

static __device__ __forceinline__ unsigned int enc4(float a, float b, float c2, float d) {
#ifdef HW_FP8
    int r = 0;
    r = __builtin_amdgcn_cvt_pk_fp8_f32(a, b, r, false);
    r = __builtin_amdgcn_cvt_pk_fp8_f32(c2, d, r, true);
    return (unsigned int)r;
#else
    return enc1(a) | (enc1(b) << 8) | (enc1(c2) << 16) | (enc1(d) << 24);
#endif
}

// ---------------- XCD-partitioned bucket-CSR build ----------------
// blockIdx = chunk*8 + part. Block scans its 4096-edge chunk, commits only edges whose
// dst lies in its partition. With round-robin block->XCD dispatch, all writers of a
// given cnt/colIdx line sit on one XCD -> no cross-L2 line ping-pong. Correct for ANY
// block->XCD mapping (each edge committed exactly once).

__global__ void fill_cap_part(const int* __restrict__ src, const int* __restrict__ dst,
                              int E, int* __restrict__ cnt, int* __restrict__ colIdx) {
    const int part = blockIdx.x & (NPART - 1);
    const int base = (blockIdx.x >> 3) * CHUNK;
    const int lo = part * (N_NODES / NPART);
    const int hi = lo + (N_NODES / NPART);
#pragma unroll
    for (int it = 0; it < CHUNK / 256; ++it) {
        int e = base + it * 256 + (int)threadIdx.x;
        if (e < E) {
            int d = dst[e];
            if (d >= lo && d < hi) {
                int slot = atomicAdd(&cnt[d], 1);
                if (slot < CAP) colIdx[(size_t)d * CAP + slot] = src[e];
            }
        }
    }
}

// ---------------- prep: fp32->bf16 converts + weight prepack, one launch ----------------

__global__ void prep_all(const float* __restrict__ x, const float* __restrict__ h,
                         unsigned short* __restrict__ xb, unsigned short* __restrict__ hb,
                         const float* __restrict__ Wq, const float* __restrict__ Wk,
                         const float* __restrict__ Wv, const float* __restrict__ Ws,
                         const float* __restrict__ bq, const float* __restrict__ bk,
                         const float* __restrict__ bv, const float* __restrict__ bs,
                         unsigned short* __restrict__ WT, float* __restrict__ ball,
                         int nCvt) {
    int b = blockIdx.x;
    if (b < nCvt) {
        int i = (b * 256 + threadIdx.x) * 4;
        if (i < NDTOT) {
            float4 fx = *(const float4*)&x[i];
            float4 fh = *(const float4*)&h[i];
            ushort4 ux, uh;
            ux.x = f2bf(fx.x); ux.y = f2bf(fx.y); ux.z = f2bf(fx.z); ux.w = f2bf(fx.w);
            uh.x = f2bf(fh.x); uh.y = f2bf(fh.y); uh.z = f2bf(fh.z); uh.w = f2bf(fh.w);
            *(ushort4*)&xb[i] = ux;
            *(ushort4*)&hb[i] = uh;
        }
    } else {
        int idx = (b - nCvt) * 256 + threadIdx.x;   // conv*16384 + n*64 + k
        if (idx >= N_CONVS * 256 * 64) return;
        int conv = idx >> 14;
        int rem = idx & 16383;
        int n = rem >> 6, kk = rem & 63;
        int mat = n >> 6, c = n & 63;
        const float* W = mat == 0 ? Wq : mat == 1 ? Wk : mat == 2 ? Wv : Ws;
        WT[idx] = f2bf(W[conv * 4096 + kk * 64 + c]);
        if (kk == 0) {
            const float* B = mat == 0 ? bq : mat == 1 ? bk : mat == 2 ? bv : bs;
            ball[conv * 256 + n] = B[conv * 64 + c];
        }
    }
}

// ---------------- pair GEMM: convA(XA) & convB(XB), swapped-operand MFMA ----------------
// 512 threads = 8 waves. wave = conv*4 + mat; mat 0..2 -> q/k/v, mat 3 -> skip.
// q -> qboth[node][128] bf16 (qA|qB); k,v -> kv8[node][256] fp8 (kA|vA|kB|vB).

static __device__ __forceinline__ void gemm_pair_body(
    const unsigned short* __restrict__ XA, const unsigned short* __restrict__ XB, int N,
    const unsigned short* __restrict__ WTA, const unsigned short* __restrict__ WTB,
    const float* __restrict__ ballA, const float* __restrict__ ballB,
    unsigned short* __restrict__ qboth, unsigned char* __restrict__ kv8,
    float* __restrict__ sk)
{
    __shared__ __align__(16) unsigned short XLA[64][72];
    __shared__ __align__(16) unsigned short XLB[64][72];
    __shared__ __align__(16) float SKIP[64][68];

    const int tid = threadIdx.x;
    const int base = blockIdx.x * 64;
    const int lane = tid & 63;
    const int wave = tid >> 6;
    const int conv = wave >> 2;
    const int mat = wave & 3;

    {
        int r = tid >> 3, cc = (tid & 7) * 8;
        uint4 va = {0u,0u,0u,0u}, vb = {0u,0u,0u,0u};
        if (base + r < N) {
            va = *(const uint4*)&XA[(size_t)(base + r) * D + cc];
            vb = *(const uint4*)&XB[(size_t)(base + r) * D + cc];
        }
        *(uint4*)&XLA[r][cc] = va;
        *(uint4*)&XLB[r][cc] = vb;
    }
    __syncthreads();

    const int l15 = lane & 15;
    const int lhi = lane >> 4;
    const int n0 = mat * 64;
    const unsigned short* WT = conv ? WTB : WTA;
    const float* ball = conv ? ballB : ballA;

    bf16x8 Wf[4][2];
#pragma unroll
    for (int ni = 0; ni < 4; ++ni)
#pragma unroll
        for (int ks = 0; ks < 2; ++ks)
            Wf[ni][ks] = *(const bf16x8*)&WT[(size_t)(n0 + ni * 16 + l15) * D + lhi * 8 + ks * 32];

    bf16x8 Xf[4][2];
#pragma unroll
    for (int mi = 0; mi < 4; ++mi)
#pragma unroll
        for (int ks = 0; ks < 2; ++ks)
            Xf[mi][ks] = conv ? *(const bf16x8*)&XLB[mi * 16 + l15][lhi * 8 + ks * 32]
                              : *(const bf16x8*)&XLA[mi * 16 + l15][lhi * 8 + ks * 32];

    f32x4 acc[4][4];
#pragma unroll
    for (int ni = 0; ni < 4; ++ni) {
        const float4 b4 = *(const float4*)&ball[n0 + ni * 16 + lhi * 4];
#pragma unroll
        for (int mi = 0; mi < 4; ++mi) {
            f32x4 t;
            t[0] = b4.x; t[1] = b4.y; t[2] = b4.z; t[3] = b4.w;
            acc[mi][ni] = t;
        }
    }

#pragma unroll
    for (int ks = 0; ks < 2; ++ks)
#pragma unroll
        for (int mi = 0; mi < 4; ++mi)
#pragma unroll
            for (int ni = 0; ni < 4; ++ni)
                acc[mi][ni] = __builtin_amdgcn_mfma_f32_16x16x32_bf16(
                    Wf[ni][ks], Xf[mi][ks], acc[mi][ni], 0, 0, 0);

    if (mat == 0) {
        unsigned short* outb = qboth + conv * 64;
#pragma unroll
        for (int mi = 0; mi < 4; ++mi) {
            int row = base + mi * 16 + l15;
            if (row < N) {
#pragma unroll
                for (int ni = 0; ni < 4; ++ni) {
                    int col = ni * 16 + lhi * 4;
                    ushort4 u;
                    u.x = f2bf(acc[mi][ni][0]); u.y = f2bf(acc[mi][ni][1]);
                    u.z = f2bf(acc[mi][ni][2]); u.w = f2bf(acc[mi][ni][3]);
                    *(ushort4*)&outb[(size_t)row * 128 + col] = u;
                }
            }
        }
    } else if (mat < 3) {
        unsigned char* outb = kv8 + conv * 128 + (mat == 2 ? 64 : 0);
#pragma unroll
        for (int mi = 0; mi < 4; ++mi) {
            int row = base + mi * 16 + l15;
            if (row < N) {
#pragma unroll
                for (int ni = 0; ni < 4; ++ni) {
                    int col = ni * 16 + lhi * 4;
                    unsigned int r = enc4(acc[mi][ni][0], acc[mi][ni][1],
                                          acc[mi][ni][2], acc[mi][ni][3]);
                    *(unsigned int*)&outb[(size_t)row * 256 + col] = r;
                }
            }
        }
    } else if (conv == 0) {
#pragma unroll
        for (int mi = 0; mi < 4; ++mi)
#pragma unroll
            for (int ni = 0; ni < 4; ++ni)
                *(f32x4*)&SKIP[mi * 16 + l15][ni * 16 + lhi * 4] = acc[mi][ni];
    }
    __syncthreads();
    if (mat == 3 && conv == 1) {
#pragma unroll
        for (int mi = 0; mi < 4; ++mi) {
            int row = base + mi * 16 + l15;
            if (row < N) {
#pragma unroll
                for (int ni = 0; ni < 4; ++ni) {
                    int col = ni * 16 + lhi * 4;
                    const f32x4 s4 = *(const f32x4*)&SKIP[mi * 16 + l15][col];
                    float4 r4;
                    r4.x = acc[mi][ni][0] + s4[0];
                    r4.y = acc[mi][ni][1] + s4[1];
                    r4.z = acc[mi][ni][2] + s4[2];
                    r4.w = acc[mi][ni][3] + s4[3];
                    *(float4*)&sk[(size_t)row * 64 + col] = r4;
                }
            }
        }
    }
}

__global__ __launch_bounds__(512) void gemm_pair(
    const unsigned short* __restrict__ XA, const unsigned short* __restrict__ XB, int N,
    const unsigned short* __restrict__ WTA, const unsigned short* __restrict__ WTB,
    const float* __restrict__ ballA, const float* __restrict__ ballB,
    unsigned short* __restrict__ qboth, unsigned char* __restrict__ kv8,
    float* __restrict__ sk)
{
    gemm_pair_body(XA, XB, N, WTA, WTB, ballA, ballB, qboth, kv8, sk);
}

// ---------------- dual-conv edge attention: 8-lane group per node, fp8 kv ----------------

__global__ __launch_bounds__(256) void edge_attn2(
    const int* __restrict__ cnt, const int* __restrict__ colIdx,
    const unsigned short* __restrict__ qboth, const unsigned char* __restrict__ kv8,
    float* __restrict__ tgt, int N)
{
    const int tid = threadIdx.x;
    const int node = blockIdx.x * 32 + (tid >> 3);
    if (node >= N) return;
    const int t = tid & 7;

    int deg = cnt[node];
    if (deg > CAP) deg = CAP;

    const float SC = 0.18033688f;  // 0.125 * log2(e)
    const uint4 qa4 = *(const uint4*)&qboth[(size_t)node * 128 + t * 8];
    const uint4 qb4 = *(const uint4*)&qboth[(size_t)node * 128 + 64 + t * 8];
    float qa[8], qb[8];
    qa[0] = lo2f(qa4.x) * SC; qa[1] = hi2f(qa4.x) * SC;
    qa[2] = lo2f(qa4.y) * SC; qa[3] = hi2f(qa4.y) * SC;
    qa[4] = lo2f(qa4.z) * SC; qa[5] = hi2f(qa4.z) * SC;
    qa[6] = lo2f(qa4.w) * SC; qa[7] = hi2f(qa4.w) * SC;
    qb[0] = lo2f(qb4.x) * SC; qb[1] = hi2f(qb4.x) * SC;
    qb[2] = lo2f(qb4.y) * SC; qb[3] = hi2f(qb4.y) * SC;
    qb[4] = lo2f(qb4.z) * SC; qb[5] = hi2f(qb4.z) * SC;
    qb[6] = lo2f(qb4.w) * SC; qb[7] = hi2f(qb4.w) * SC;

    const size_t rowbase = (size_t)node * CAP;

    float l0 = 0.0f, l1 = 0.0f;
    float a0[8], a1[8];
#pragma unroll
    for (int i = 0; i < 8; ++i) { a0[i] = 0.0f; a1[i] = 0.0f; }

    for (int j = 0; j < deg; j += 2) {
        const bool v2 = (j + 1) < deg;
        const int s1 = colIdx[rowbase + j];
        const int s2 = colIdx[rowbase + (v2 ? j + 1 : j)];
        const unsigned char* p1 = kv8 + (size_t)s1 * 256 + t * 8;
        const unsigned char* p2 = kv8 + (size_t)s2 * 256 + t * 8;
        const uint2 ka1 = *(const uint2*)p1;
        const uint2 va1 = *(const uint2*)(p1 + 64);
        const uint2 kb1 = *(const uint2*)(p1 + 128);
        const uint2 vb1 = *(const uint2*)(p1 + 192);
        const uint2 ka2 = *(const uint2*)p2;
        const uint2 va2 = *(const uint2*)(p2 + 64);
        const uint2 kb2 = *(const uint2*)(p2 + 128);
        const uint2 vb2 = *(const uint2*)(p2 + 192);

        float kf[8];
        dec8(ka1.x, ka1.y, kf);
        float pa1 = qa[0]*kf[0] + qa[1]*kf[1] + qa[2]*kf[2] + qa[3]*kf[3]
                  + qa[4]*kf[4] + qa[5]*kf[5] + qa[6]*kf[6] + qa[7]*kf[7];
        dec8(kb1.x, kb1.y, kf);
        float pb1 = qb[0]*kf[0] + qb[1]*kf[1] + qb[2]*kf[2] + qb[3]*kf[3]
                  + qb[4]*kf[4] + qb[5]*kf[5] + qb[6]*kf[6] + qb[7]*kf[7];
        dec8(ka2.x, ka2.y, kf);
        float pa2 = qa[0]*kf[0] + qa[1]*kf[1] + qa[2]*kf[2] + qa[3]*kf[3]
                  + qa[4]*kf[4] + qa[5]*kf[5] + qa[6]*kf[6] + qa[7]*kf[7];
        dec8(kb2.x, kb2.y, kf);
        float pb2 = qb[0]*kf[0] + qb[1]*kf[1] + qb[2]*kf[2] + qb[3]*kf[3]
                  + qb[4]*kf[4] + qb[5]*kf[5] + qb[6]*kf[6] + qb[7]*kf[7];

        pa1 += __shfl_xor(pa1, 1); pb1 += __shfl_xor(pb1, 1);
        pa2 += __shfl_xor(pa2, 1); pb2 += __shfl_xor(pb2, 1);
        pa1 += __shfl_xor(pa1, 2); pb1 += __shfl_xor(pb1, 2);
        pa2 += __shfl_xor(pa2, 2); pb2 += __shfl_xor(pb2, 2);
        pa1 += __shfl_xor(pa1, 4); pb1 += __shfl_xor(pb1, 4);
        pa2 += __shfl_xor(pa2, 4); pb2 += __shfl_xor(pb2, 4);

        const float w01 = exp2f(pa1);
        const float w11 = exp2f(pb1);
        const float w02 = v2 ? exp2f(pa2) : 0.0f;
        const float w12 = v2 ? exp2f(pb2) : 0.0f;
        l0 += w01 + w02; l1 += w11 + w12;

        float vf1[8], vf2[8];
        dec8(va1.x, va1.y, vf1);
        dec8(va2.x, va2.y, vf2);
#pragma unroll
        for (int i = 0; i < 8; ++i) a0[i] += w01 * vf1[i] + w02 * vf2[i];
        dec8(vb1.x, vb1.y, vf1);
        dec8(vb2.x, vb2.y, vf2);
#pragma unroll
        for (int i = 0; i < 8; ++i) a1[i] += w11 * vf1[i] + w12 * vf2[i];
    }

    const float inv0 = 1.0f / (l0 + 1e-16f);
    const float inv1 = 1.0f / (l1 + 1e-16f);
    float* pout = &tgt[(size_t)node * 64 + t * 8];
    float4 o1 = *(float4*)pout;
    float4 o2 = *(float4*)(pout + 4);
    o1.x += a0[0] * inv0 + a1[0] * inv1;
    o1.y += a0[1] * inv0 + a1[1] * inv1;
    o1.z += a0[2] * inv0 + a1[2] * inv1;
    o1.w += a0[3] * inv0 + a1[3] * inv1;
    o2.x += a0[4] * inv0 + a1[4] * inv1;
    o2.y += a0[5] * inv0 + a1[5] * inv1;
    o2.z += a0[6] * inv0 + a1[6] * inv1;
    o2.w += a0[7] * inv0 + a1[7] * inv1;
    *(float4*)pout = o1;
    *(float4*)(pout + 4) = o2;
}

// ---------------- elementwise (vectorized x4) ----------------

__global__ void rh_kernel(const float* __restrict__ rpre, const float* __restrict__ h,
                          unsigned short* __restrict__ rhb, int n) {
    int i = (blockIdx.x * 256 + threadIdx.x) * 4;
    if (i < n) {
        float4 rp = *(const float4*)&rpre[i];
        float4 hh = *(const float4*)&h[i];
        ushort4 o;
        o.x = f2bf(hh.x / (1.0f + __expf(-rp.x)));
        o.y = f2bf(hh.y / (1.0f + __expf(-rp.y)));
        o.z = f2bf(hh.z / (1.0f + __expf(-rp.z)));
        o.w = f2bf(hh.w / (1.0f + __expf(-rp.w)));
        *(ushort4*)&rhb[i] = o;
    }
}

__global__ void final_kernel(const float* __restrict__ zpre, const float* __restrict__ h,
                             const float* __restrict__ c45, float* __restrict__ out, int n) {
    int i = (blockIdx.x * 256 + threadIdx.x) * 4;
    if (i < n) {
        float4 zp = *(const float4*)&zpre[i];
        float4 hh = *(const float4*)&h[i];
        float4 cc = *(const float4*)&c45[i];
        float4 r;
        float z0 = 1.0f / (1.0f + __expf(-zp.x));
        float z1 = 1.0f / (1.0f + __expf(-zp.y));
        float z2 = 1.0f / (1.0f + __expf(-zp.z));
        float z3 = 1.0f / (1.0f + __expf(-zp.w));
        r.x = z0 * hh.x + (1.0f - z0) * tanhf(cc.x);
        r.y = z1 * hh.y + (1.0f - z1) * tanhf(cc.y);
        r.z = z2 * hh.z + (1.0f - z2) * tanhf(cc.z);
        r.w = z3 * hh.w + (1.0f - z3) * tanhf(cc.w);
        *(float4*)&out[i] = r;
    }
}

// ---------------- launch ----------------

extern "C" void kernel_launch(void* const* d_in, const int* in_sizes, int n_in,
                              void* d_out, int out_size, void* d_ws, size_t ws_size,
                              hipStream_t stream) {
    const int N = N_NODES, E = N_EDGES;
    const float* x  = (const float*)d_in[0];
    const float* h  = (const float*)d_in[1];
    const int*  ei  = (const int*)d_in[2];
    const float* Wq = (const float*)d_in[3];
    const float* bq = (const float*)d_in[4];
    const float* Wk = (const float*)d_in[5];
    const float* bk = (const float*)d_in[6];
    const float* Wv = (const float*)d_in[7];
    const float* bv = (const float*)d_in[8];
    const float* Ws = (const float*)d_in[9];
    const float* bs = (const float*)d_in[10];
    float* out = (float*)d_out;

    const int* src = ei;
    const int* dst = ei + E;

    // ---- workspace layout ----
    char* w = (char*)d_ws;
    int* cnt    = (int*)w;                        // N
    int* colIdx = cnt + N;                        // N*CAP
    size_t intWords = (size_t)N + (size_t)N * CAP;
    char* p = w + ((intWords * 4 + 255) & ~(size_t)255);

    const size_t ND = (size_t)N * D;
    float* zpre = (float*)p;            p += ND * 4;
    float* rpre = (float*)p;            p += ND * 4;
    float* c45  = (float*)p;            p += ND * 4;
    float* ball = (float*)p;            p += N_CONVS * 256 * 4;
    unsigned short* xb    = (unsigned short*)p; p += ND * 2;
    unsigned short* hb    = (unsigned short*)p; p += ND * 2;
    unsigned short* rhb   = (unsigned short*)p; p += ND * 2;
    unsigned short* qboth = (unsigned short*)p; p += ND * 2 * 2;   // [N][128] bf16
    unsigned char*  kv8   = (unsigned char*)p;  p += (size_t)N_NODES * 256;  // [N][256] fp8
    unsigned short* WT    = (unsigned short*)p; p += (size_t)N_CONVS * 256 * 64 * 2;

    const int NB_CVT = (int)(ND / 4 / 256);             // 6250 (exact)
    const int NB_PP = (N_CONVS * 256 * 64 + 255) / 256; // 384
    const int NB_GEMM = (N + 63) / 64;                  // 1563
    const int NB_FILL = ((E + CHUNK - 1) / CHUNK) * NPART;  // 245*8 = 1960
    const int NB_ATTN = (N + 31) / 32;                  // 3125
    const int NB_EW = (int)(ND / 4 / 256);              // 6250

    prep_all<<<NB_CVT + NB_PP, 256, 0, stream>>>(x, h, xb, hb, Wq, Wk, Wv, Ws,
                                                 bq, bk, bv, bs, WT, ball, NB_CVT);
    hipMemsetAsync(cnt, 0, (size_t)N * sizeof(int), stream);
    fill_cap_part<<<NB_FILL, 256, 0, stream>>>(src, dst, E, cnt, colIdx);

#define WTc(i) (WT + (size_t)(i) * 256 * 64)
#define BLc(i) (ball + (size_t)(i) * 256)

    // pair (0,1) -> zpre
    gemm_pair<<<NB_GEMM, 512, 0, stream>>>(
        xb, hb, N, WTc(0), WTc(1), BLc(0), BLc(1), qboth, kv8, zpre);
    edge_attn2<<<NB_ATTN, 256, 0, stream>>>(cnt, colIdx, qboth, kv8, zpre, N);

    // pair (2,3) -> rpre
    gemm_pair<<<NB_GEMM, 512, 0, stream>>>(
        xb, hb, N, WTc(2), WTc(3), BLc(2), BLc(3), qboth, kv8, rpre);
    edge_attn2<<<NB_ATTN, 256, 0, stream>>>(cnt, colIdx, qboth, kv8, rpre, N);

    // rh, then pair (4,5) -> c45
    rh_kernel<<<NB_EW, 256, 0, stream>>>(rpre, h, rhb, (int)ND);
    gemm_pair<<<NB_GEMM, 512, 0, stream>>>(
        xb, rhb, N, WTc(4), WTc(5), BLc(4), BLc(5), qboth, kv8, c45);
    edge_attn2<<<NB_ATTN, 256, 0, stream>>>(cnt, colIdx, qboth, kv8, c45, N);

    final_kernel<<<NB_EW, 256, 0, stream>>>(zpre, h, c45, out, (int)ND);

#undef WTc
#undef BLc
}

// Round 11
// 357.819 us; speedup vs baseline: 1.4356x; 1.0505x over previous
//
#include <hip/hip_runtime.h>
#include <math.h>

#define N_NODES 100000
#define N_EDGES 1000000
#define D 64
#define N_CONVS 6
#define CAP 64  // max degree bucket (Poisson(10): P(deg>64) ~ 1e-30/node)
#define NDTOT (N_NODES * D)
#define NPART 8           // = XCD count; N_NODES/NPART = 12500 exact
#define CHUNK 4096        // edges per chunk-block

typedef __bf16 bf16x8 __attribute__((ext_vector_type(8)));
typedef float f32x4 __attribute__((ext_vector_type(4)));
typedef float f32x2 __attribute__((ext_vector_type(2)));

static __device__ __forceinline__ float hi2f(unsigned int d) {
    union { unsigned int i; float f; } c; c.i = d & 0xFFFF0000u; return c.f;
}
static __device__ __forceinline__ float lo2f(unsigned int d) {
    union { unsigned int i; float f; } c; c.i = d << 16; return c.f;
}
static __device__ __forceinline__ unsigned short f2bf(float f) {
    union { float f; unsigned int i; } c; c.f = f;
    unsigned int x = c.i;
    unsigned int r = (x + 0x7fffu + ((x >> 16) & 1u)) >> 16;
    return (unsigned short)r;
}

// ---------------- fp8 e4m3 helpers (HW cvt on gfx950; software fallback) ----------------

#if __has_builtin(__builtin_amdgcn_cvt_pk_f32_fp8) && __has_builtin(__builtin_amdgcn_cvt_pk_fp8_f32)
#define HW_FP8 1
#endif

#ifndef HW_FP8
static __device__ __forceinline__ float dec1(unsigned int b) {
    union { unsigned int i; float f; } c;
    c.i = ((b & 0x80u) << 24) | ((b & 0x7fu) << 20);
    return c.f * 0x1p+120f;
}
static __device__ __forceinline__ unsigned int enc1(float f) {
    union { float f; unsigned int i; } c; c.f = f;
    unsigned int s = (c.i >> 24) & 0x80u;
    float a = fabsf(f);
    a = fminf(a, 448.0f);
    c.f = a * 0x1p-120f;
    unsigned int u = c.i;
    unsigned int bits = (u + 0x7FFFFu + ((u >> 20) & 1u)) >> 20;
    if (bits > 0x7Eu) bits = 0x7Eu;
    return s | bits;
}
#endif

static __device__ __forceinline__ void dec8(unsigned int lo, unsigned int hi, float* f) {
#ifdef HW_FP8
    f32x2 p0 = __builtin_amdgcn_cvt_pk_f32_fp8(lo, false);
    f32x2 p1 = __builtin_amdgcn_cvt_pk_f32_fp8(lo, true);
    f32x2 p2 = __builtin_amdgcn_cvt_pk_f32_fp8(hi, false);
    f32x2 p3 = __builtin_amdgcn_cvt_pk_f32_fp8(hi, true);
    f[0] = p0[0]; f[1] = p0[1]; f[2] = p1[0]; f[3] = p1[1];
    f[4] = p2[0]; f[5] = p2[1]; f[6] = p3[0]; f[7] = p3[1];
#else
#pragma unroll
    for (int i = 0; i < 4; ++i) f[i] = dec1((lo >> (8 * i)) & 0xFFu);
#pragma unroll
    for (int i = 0; i < 4; ++i) f[4 + i] = dec1((hi >> (8 * i)) & 0xFFu);
#endif
}

static __device__ __forceinline__ unsigned int enc4(float a, float b, float c2, float d) {
#ifdef HW_FP8
    int r = 0;
    r = __builtin_amdgcn_cvt_pk_fp8_f32(a, b, r, false);
    r = __builtin_amdgcn_cvt_pk_fp8_f32(c2, d, r, true);
    return (unsigned int)r;
#else
    return enc1(a) | (enc1(b) << 8) | (enc1(c2) << 16) | (enc1(d) << 24);
#endif
}

// ---------------- XCD-partitioned bucket-CSR build ----------------

__global__ void fill_cap_part(const int* __restrict__ src, const int* __restrict__ dst,
                              int E, int* __restrict__ cnt, int* __restrict__ colIdx) {
    const int part = blockIdx.x & (NPART - 1);
    const int base = (blockIdx.x >> 3) * CHUNK;
    const int lo = part * (N_NODES / NPART);
    const int hi = lo + (N_NODES / NPART);
#pragma unroll
    for (int it = 0; it < CHUNK / 256; ++it) {
        int e = base + it * 256 + (int)threadIdx.x;
        if (e < E) {
            int d = dst[e];
            if (d >= lo && d < hi) {
                int slot = atomicAdd(&cnt[d], 1);
                if (slot < CAP) colIdx[(size_t)d * CAP + slot] = src[e];
            }
        }
    }
}

// ---------------- prep: fp32->bf16 converts + weight prepack, one launch ----------------

__global__ void prep_all(const float* __restrict__ x, const float* __restrict__ h,
                         unsigned short* __restrict__ xb, unsigned short* __restrict__ hb,
                         const float* __restrict__ Wq, const float* __restrict__ Wk,
                         const float* __restrict__ Wv, const float* __restrict__ Ws,
                         const float* __restrict__ bq, const float* __restrict__ bk,
                         const float* __restrict__ bv, const float* __restrict__ bs,
                         unsigned short* __restrict__ WT, float* __restrict__ ball,
                         int nCvt) {
    int b = blockIdx.x;
    if (b < nCvt) {
        int i = (b * 256 + threadIdx.x) * 4;
        if (i < NDTOT) {
            float4 fx = *(const float4*)&x[i];
            float4 fh = *(const float4*)&h[i];
            ushort4 ux, uh;
            ux.x = f2bf(fx.x); ux.y = f2bf(fx.y); ux.z = f2bf(fx.z); ux.w = f2bf(fx.w);
            uh.x = f2bf(fh.x); uh.y = f2bf(fh.y); uh.z = f2bf(fh.z); uh.w = f2bf(fh.w);
            *(ushort4*)&xb[i] = ux;
            *(ushort4*)&hb[i] = uh;
        }
    } else {
        int idx = (b - nCvt) * 256 + threadIdx.x;   // conv*16384 + n*64 + k
        if (idx >= N_CONVS * 256 * 64) return;
        int conv = idx >> 14;
        int rem = idx & 16383;
        int n = rem >> 6, kk = rem & 63;
        int mat = n >> 6, c = n & 63;
        const float* W = mat == 0 ? Wq : mat == 1 ? Wk : mat == 2 ? Wv : Ws;
        WT[idx] = f2bf(W[conv * 4096 + kk * 64 + c]);
        if (kk == 0) {
            const float* B = mat == 0 ? bq : mat == 1 ? bk : mat == 2 ? bv : bs;
            ball[conv * 256 + n] = B[conv * 64 + c];
        }
    }
}

// ---------------- quad GEMM: convs 0..3 sharing staged x/h tiles ----------------
// 512 threads = 8 waves; wave = cSel*4 + mat (cSel: 0 -> input XA, 1 -> input XB).
// Loop pp: pp=0 -> convs {0,1} (q0|q1, kv8a, zskip); pp=1 -> convs {2,3} (q2|q3, kv8b, rskip).
// Swapped-operand MFMA: D col(l15) = node row, reg r -> output col lhi*4+r.

__global__ __launch_bounds__(512) void gemm_quad(
    const unsigned short* __restrict__ XA, const unsigned short* __restrict__ XB, int N,
    const unsigned short* __restrict__ WT4, const float* __restrict__ ball4,
    unsigned short* __restrict__ qboth2,    // [N][256]: q0|q1|q2|q3 bf16
    unsigned char* __restrict__ kv8a,       // [N][256]: k0|v0|k1|v1 fp8
    unsigned char* __restrict__ kv8b,       // [N][256]: k2|v2|k3|v3 fp8
    float* __restrict__ zskip, float* __restrict__ rskip)
{
    __shared__ __align__(16) unsigned short XLA[64][72];
    __shared__ __align__(16) unsigned short XLB[64][72];
    __shared__ __align__(16) float SKIP[64][68];

    const int tid = threadIdx.x;
    const int base = blockIdx.x * 64;
    const int lane = tid & 63;
    const int wave = tid >> 6;
    const int cSel = wave >> 2;
    const int mat = wave & 3;

    {
        int r = tid >> 3, cc = (tid & 7) * 8;
        uint4 va = {0u,0u,0u,0u}, vb = {0u,0u,0u,0u};
        if (base + r < N) {
            va = *(const uint4*)&XA[(size_t)(base + r) * D + cc];
            vb = *(const uint4*)&XB[(size_t)(base + r) * D + cc];
        }
        *(uint4*)&XLA[r][cc] = va;
        *(uint4*)&XLB[r][cc] = vb;
    }
    __syncthreads();

    const int l15 = lane & 15;
    const int lhi = lane >> 4;
    const int n0 = mat * 64;

    bf16x8 Xf[4][2];
#pragma unroll
    for (int mi = 0; mi < 4; ++mi)
#pragma unroll
        for (int ks = 0; ks < 2; ++ks)
            Xf[mi][ks] = cSel ? *(const bf16x8*)&XLB[mi * 16 + l15][lhi * 8 + ks * 32]
                              : *(const bf16x8*)&XLA[mi * 16 + l15][lhi * 8 + ks * 32];

#pragma unroll
    for (int pp = 0; pp < 2; ++pp) {
        const int conv = pp * 2 + cSel;
        const unsigned short* WT = WT4 + (size_t)conv * 256 * 64;
        const float* ball = ball4 + conv * 256;

        bf16x8 Wf[4][2];
#pragma unroll
        for (int ni = 0; ni < 4; ++ni)
#pragma unroll
            for (int ks = 0; ks < 2; ++ks)
                Wf[ni][ks] = *(const bf16x8*)&WT[(size_t)(n0 + ni * 16 + l15) * D + lhi * 8 + ks * 32];

        f32x4 acc[4][4];
#pragma unroll
        for (int ni = 0; ni < 4; ++ni) {
            const float4 b4 = *(const float4*)&ball[n0 + ni * 16 + lhi * 4];
#pragma unroll
            for (int mi = 0; mi < 4; ++mi) {
                f32x4 t;
                t[0] = b4.x; t[1] = b4.y; t[2] = b4.z; t[3] = b4.w;
                acc[mi][ni] = t;
            }
        }

#pragma unroll
        for (int ks = 0; ks < 2; ++ks)
#pragma unroll
            for (int mi = 0; mi < 4; ++mi)
#pragma unroll
                for (int ni = 0; ni < 4; ++ni)
                    acc[mi][ni] = __builtin_amdgcn_mfma_f32_16x16x32_bf16(
                        Wf[ni][ks], Xf[mi][ks], acc[mi][ni], 0, 0, 0);

        if (mat == 0) {
            unsigned short* outb = qboth2 + pp * 128 + cSel * 64;
#pragma unroll
            for (int mi = 0; mi < 4; ++mi) {
                int row = base + mi * 16 + l15;
                if (row < N) {
#pragma unroll
                    for (int ni = 0; ni < 4; ++ni) {
                        int col = ni * 16 + lhi * 4;
                        ushort4 u;
                        u.x = f2bf(acc[mi][ni][0]); u.y = f2bf(acc[mi][ni][1]);
                        u.z = f2bf(acc[mi][ni][2]); u.w = f2bf(acc[mi][ni][3]);
                        *(ushort4*)&outb[(size_t)row * 256 + col] = u;
                    }
                }
            }
        } else if (mat < 3) {
            unsigned char* outb = (pp ? kv8b : kv8a) + cSel * 128 + (mat == 2 ? 64 : 0);
#pragma unroll
            for (int mi = 0; mi < 4; ++mi) {
                int row = base + mi * 16 + l15;
                if (row < N) {
#pragma unroll
                    for (int ni = 0; ni < 4; ++ni) {
                        int col = ni * 16 + lhi * 4;
                        unsigned int r = enc4(acc[mi][ni][0], acc[mi][ni][1],
                                              acc[mi][ni][2], acc[mi][ni][3]);
                        *(unsigned int*)&outb[(size_t)row * 256 + col] = r;
                    }
                }
            }
        } else if (cSel == 0) {
#pragma unroll
            for (int mi = 0; mi < 4; ++mi)
#pragma unroll
                for (int ni = 0; ni < 4; ++ni)
                    *(f32x4*)&SKIP[mi * 16 + l15][ni * 16 + lhi * 4] = acc[mi][ni];
        }
        __syncthreads();
        if (mat == 3 && cSel == 1) {
            float* skout = pp ? rskip : zskip;
#pragma unroll
            for (int mi = 0; mi < 4; ++mi) {
                int row = base + mi * 16 + l15;
                if (row < N) {
#pragma unroll
                    for (int ni = 0; ni < 4; ++ni) {
                        int col = ni * 16 + lhi * 4;
                        const f32x4 s4 = *(const f32x4*)&SKIP[mi * 16 + l15][col];
                        float4 r4;
                        r4.x = acc[mi][ni][0] + s4[0];
                        r4.y = acc[mi][ni][1] + s4[1];
                        r4.z = acc[mi][ni][2] + s4[2];
                        r4.w = acc[mi][ni][3] + s4[3];
                        *(float4*)&skout[(size_t)row * 64 + col] = r4;
                    }
                }
            }
        }
        __syncthreads();   // protect SKIP reuse across pp
    }
}

// ---------------- pair GEMM (convs 4,5): as gemm_quad but one pair ----------------

__global__ __launch_bounds__(512) void gemm_pair(
    const unsigned short* __restrict__ XA, const unsigned short* __restrict__ XB, int N,
    const unsigned short* __restrict__ WTA, const unsigned short* __restrict__ WTB,
    const float* __restrict__ ballA, const float* __restrict__ ballB,
    unsigned short* __restrict__ qboth, unsigned char* __restrict__ kv8,
    float* __restrict__ sk)
{
    __shared__ __align__(16) unsigned short XLA[64][72];
    __shared__ __align__(16) unsigned short XLB[64][72];
    __shared__ __align__(16) float SKIP[64][68];

    const int tid = threadIdx.x;
    const int base = blockIdx.x * 64;
    const int lane = tid & 63;
    const int wave = tid >> 6;
    const int conv = wave >> 2;
    const int mat = wave & 3;

    {
        int r = tid >> 3, cc = (tid & 7) * 8;
        uint4 va = {0u,0u,0u,0u}, vb = {0u,0u,0u,0u};
        if (base + r < N) {
            va = *(const uint4*)&XA[(size_t)(base + r) * D + cc];
            vb = *(const uint4*)&XB[(size_t)(base + r) * D + cc];
        }
        *(uint4*)&XLA[r][cc] = va;
        *(uint4*)&XLB[r][cc] = vb;
    }
    __syncthreads();

    const int l15 = lane & 15;
    const int lhi = lane >> 4;
    const int n0 = mat * 64;
    const unsigned short* WT = conv ? WTB : WTA;
    const float* ball = conv ? ballB : ballA;

    bf16x8 Wf[4][2];
#pragma unroll
    for (int ni = 0; ni < 4; ++ni)
#pragma unroll
        for (int ks = 0; ks < 2; ++ks)
            Wf[ni][ks] = *(const bf16x8*)&WT[(size_t)(n0 + ni * 16 + l15) * D + lhi * 8 + ks * 32];

    bf16x8 Xf[4][2];
#pragma unroll
    for (int mi = 0; mi < 4; ++mi)
#pragma unroll
        for (int ks = 0; ks < 2; ++ks)
            Xf[mi][ks] = conv ? *(const bf16x8*)&XLB[mi * 16 + l15][lhi * 8 + ks * 32]
                              : *(const bf16x8*)&XLA[mi * 16 + l15][lhi * 8 + ks * 32];

    f32x4 acc[4][4];
#pragma unroll
    for (int ni = 0; ni < 4; ++ni) {
        const float4 b4 = *(const float4*)&ball[n0 + ni * 16 + lhi * 4];
#pragma unroll
        for (int mi = 0; mi < 4; ++mi) {
            f32x4 t;
            t[0] = b4.x; t[1] = b4.y; t[2] = b4.z; t[3] = b4.w;
            acc[mi][ni] = t;
        }
    }

#pragma unroll
    for (int ks = 0; ks < 2; ++ks)
#pragma unroll
        for (int mi = 0; mi < 4; ++mi)
#pragma unroll
            for (int ni = 0; ni < 4; ++ni)
                acc[mi][ni] = __builtin_amdgcn_mfma_f32_16x16x32_bf16(
                    Wf[ni][ks], Xf[mi][ks], acc[mi][ni], 0, 0, 0);

    if (mat == 0) {
        unsigned short* outb = qboth + conv * 64;
#pragma unroll
        for (int mi = 0; mi < 4; ++mi) {
            int row = base + mi * 16 + l15;
            if (row < N) {
#pragma unroll
                for (int ni = 0; ni < 4; ++ni) {
                    int col = ni * 16 + lhi * 4;
                    ushort4 u;
                    u.x = f2bf(acc[mi][ni][0]); u.y = f2bf(acc[mi][ni][1]);
                    u.z = f2bf(acc[mi][ni][2]); u.w = f2bf(acc[mi][ni][3]);
                    *(ushort4*)&outb[(size_t)row * 128 + col] = u;
                }
            }
        }
    } else if (mat < 3) {
        unsigned char* outb = kv8 + conv * 128 + (mat == 2 ? 64 : 0);
#pragma unroll
        for (int mi = 0; mi < 4; ++mi) {
            int row = base + mi * 16 + l15;
            if (row < N) {
#pragma unroll
                for (int ni = 0; ni < 4; ++ni) {
                    int col = ni * 16 + lhi * 4;
                    unsigned int r = enc4(acc[mi][ni][0], acc[mi][ni][1],
                                          acc[mi][ni][2], acc[mi][ni][3]);
                    *(unsigned int*)&outb[(size_t)row * 256 + col] = r;
                }
            }
        }
    } else if (conv == 0) {
#pragma unroll
        for (int mi = 0; mi < 4; ++mi)
#pragma unroll
            for (int ni = 0; ni < 4; ++ni)
                *(f32x4*)&SKIP[mi * 16 + l15][ni * 16 + lhi * 4] = acc[mi][ni];
    }
    __syncthreads();
    if (mat == 3 && conv == 1) {
#pragma unroll
        for (int mi = 0; mi < 4; ++mi) {
            int row = base + mi * 16 + l15;
            if (row < N) {
#pragma unroll
                for (int ni = 0; ni < 4; ++ni) {
                    int col = ni * 16 + lhi * 4;
                    const f32x4 s4 = *(const f32x4*)&SKIP[mi * 16 + l15][col];
                    float4 r4;
                    r4.x = acc[mi][ni][0] + s4[0];
                    r4.y = acc[mi][ni][1] + s4[1];
                    r4.z = acc[mi][ni][2] + s4[2];
                    r4.w = acc[mi][ni][3] + s4[3];
                    *(float4*)&sk[(size_t)row * 64 + col] = r4;
                }
            }
        }
    }
}

// ---------------- dual-conv edge attention, fused epilogues ----------------
// MODE 0: tgt RMW (zpre += agg).           [pass Z]
// MODE 1: rhb = bf16(sigmoid(skip+agg)*h). [pass R: rpre never materialized]
// MODE 2: out = z*h + (1-z)*tanh(skip+agg), z = sigmoid(zpre). [pass C + final]

template<int MODE>
__global__ __launch_bounds__(256) void edge_attn_t(
    const int* __restrict__ cnt, const int* __restrict__ colIdx,
    const unsigned short* __restrict__ qptr, int qstride,
    const unsigned char* __restrict__ kv8,
    const float* __restrict__ skip, const float* __restrict__ zpre,
    const float* __restrict__ hfull,
    float* __restrict__ tgt, unsigned short* __restrict__ rhb, int N)
{
    const int tid = threadIdx.x;
    const int node = blockIdx.x * 32 + (tid >> 3);
    if (node >= N) return;
    const int t = tid & 7;

    int deg = cnt[node];
    if (deg > CAP) deg = CAP;

    const float SC = 0.18033688f;  // 0.125 * log2(e)
    const uint4 qa4 = *(const uint4*)&qptr[(size_t)node * qstride + t * 8];
    const uint4 qb4 = *(const uint4*)&qptr[(size_t)node * qstride + 64 + t * 8];
    float qa[8], qb[8];
    qa[0] = lo2f(qa4.x) * SC; qa[1] = hi2f(qa4.x) * SC;
    qa[2] = lo2f(qa4.y) * SC; qa[3] = hi2f(qa4.y) * SC;
    qa[4] = lo2f(qa4.z) * SC; qa[5] = hi2f(qa4.z) * SC;
    qa[6] = lo2f(qa4.w) * SC; qa[7] = hi2f(qa4.w) * SC;
    qb[0] = lo2f(qb4.x) * SC; qb[1] = hi2f(qb4.x) * SC;
    qb[2] = lo2f(qb4.y) * SC; qb[3] = hi2f(qb4.y) * SC;
    qb[4] = lo2f(qb4.z) * SC; qb[5] = hi2f(qb4.z) * SC;
    qb[6] = lo2f(qb4.w) * SC; qb[7] = hi2f(qb4.w) * SC;

    const size_t rowbase = (size_t)node * CAP;

    float l0 = 0.0f, l1 = 0.0f;
    float a0[8], a1[8];
#pragma unroll
    for (int i = 0; i < 8; ++i) { a0[i] = 0.0f; a1[i] = 0.0f; }

    for (int j = 0; j < deg; j += 2) {
        const bool v2 = (j + 1) < deg;
        const int s1 = colIdx[rowbase + j];
        const int s2 = colIdx[rowbase + (v2 ? j + 1 : j)];
        const unsigned char* p1 = kv8 + (size_t)s1 * 256 + t * 8;
        const unsigned char* p2 = kv8 + (size_t)s2 * 256 + t * 8;
        const uint2 ka1 = *(const uint2*)p1;
        const uint2 va1 = *(const uint2*)(p1 + 64);
        const uint2 kb1 = *(const uint2*)(p1 + 128);
        const uint2 vb1 = *(const uint2*)(p1 + 192);
        const uint2 ka2 = *(const uint2*)p2;
        const uint2 va2 = *(const uint2*)(p2 + 64);
        const uint2 kb2 = *(const uint2*)(p2 + 128);
        const uint2 vb2 = *(const uint2*)(p2 + 192);

        float kf[8];
        dec8(ka1.x, ka1.y, kf);
        float pa1 = qa[0]*kf[0] + qa[1]*kf[1] + qa[2]*kf[2] + qa[3]*kf[3]
                  + qa[4]*kf[4] + qa[5]*kf[5] + qa[6]*kf[6] + qa[7]*kf[7];
        dec8(kb1.x, kb1.y, kf);
        float pb1 = qb[0]*kf[0] + qb[1]*kf[1] + qb[2]*kf[2] + qb[3]*kf[3]
                  + qb[4]*kf[4] + qb[5]*kf[5] + qb[6]*kf[6] + qb[7]*kf[7];
        dec8(ka2.x, ka2.y, kf);
        float pa2 = qa[0]*kf[0] + qa[1]*kf[1] + qa[2]*kf[2] + qa[3]*kf[3]
                  + qa[4]*kf[4] + qa[5]*kf[5] + qa[6]*kf[6] + qa[7]*kf[7];
        dec8(kb2.x, kb2.y, kf);
        float pb2 = qb[0]*kf[0] + qb[1]*kf[1] + qb[2]*kf[2] + qb[3]*kf[3]
                  + qb[4]*kf[4] + qb[5]*kf[5] + qb[6]*kf[6] + qb[7]*kf[7];

        pa1 += __shfl_xor(pa1, 1); pb1 += __shfl_xor(pb1, 1);
        pa2 += __shfl_xor(pa2, 1); pb2 += __shfl_xor(pb2, 1);
        pa1 += __shfl_xor(pa1, 2); pb1 += __shfl_xor(pb1, 2);
        pa2 += __shfl_xor(pa2, 2); pb2 += __shfl_xor(pb2, 2);
        pa1 += __shfl_xor(pa1, 4); pb1 += __shfl_xor(pb1, 4);
        pa2 += __shfl_xor(pa2, 4); pb2 += __shfl_xor(pb2, 4);

        const float w01 = exp2f(pa1);
        const float w11 = exp2f(pb1);
        const float w02 = v2 ? exp2f(pa2) : 0.0f;
        const float w12 = v2 ? exp2f(pb2) : 0.0f;
        l0 += w01 + w02; l1 += w11 + w12;

        float vf1[8], vf2[8];
        dec8(va1.x, va1.y, vf1);
        dec8(va2.x, va2.y, vf2);
#pragma unroll
        for (int i = 0; i < 8; ++i) a0[i] += w01 * vf1[i] + w02 * vf2[i];
        dec8(vb1.x, vb1.y, vf1);
        dec8(vb2.x, vb2.y, vf2);
#pragma unroll
        for (int i = 0; i < 8; ++i) a1[i] += w11 * vf1[i] + w12 * vf2[i];
    }

    const float inv0 = 1.0f / (l0 + 1e-16f);
    const float inv1 = 1.0f / (l1 + 1e-16f);
    float o[8];
#pragma unroll
    for (int i = 0; i < 8; ++i) o[i] = a0[i] * inv0 + a1[i] * inv1;

    const size_t off = (size_t)node * 64 + t * 8;

    if (MODE == 0) {
        float* pout = &tgt[off];
        float4 o1 = *(float4*)pout;
        float4 o2 = *(float4*)(pout + 4);
        o1.x += o[0]; o1.y += o[1]; o1.z += o[2]; o1.w += o[3];
        o2.x += o[4]; o2.y += o[5]; o2.z += o[6]; o2.w += o[7];
        *(float4*)pout = o1;
        *(float4*)(pout + 4) = o2;
    } else if (MODE == 1) {
        const float4 s1 = *(const float4*)&skip[off];
        const float4 s2 = *(const float4*)&skip[off + 4];
        const float4 h1 = *(const float4*)&hfull[off];
        const float4 h2 = *(const float4*)&hfull[off + 4];
        ushort4 u1, u2;
        u1.x = f2bf(h1.x / (1.0f + __expf(-(s1.x + o[0]))));
        u1.y = f2bf(h1.y / (1.0f + __expf(-(s1.y + o[1]))));
        u1.z = f2bf(h1.z / (1.0f + __expf(-(s1.z + o[2]))));
        u1.w = f2bf(h1.w / (1.0f + __expf(-(s1.w + o[3]))));
        u2.x = f2bf(h2.x / (1.0f + __expf(-(s2.x + o[4]))));
        u2.y = f2bf(h2.y / (1.0f + __expf(-(s2.y + o[5]))));
        u2.z = f2bf(h2.z / (1.0f + __expf(-(s2.z + o[6]))));
        u2.w = f2bf(h2.w / (1.0f + __expf(-(s2.w + o[7]))));
        *(ushort4*)&rhb[off] = u1;
        *(ushort4*)&rhb[off + 4] = u2;
    } else {
        const float4 s1 = *(const float4*)&skip[off];
        const float4 s2 = *(const float4*)&skip[off + 4];
        const float4 z1 = *(const float4*)&zpre[off];
        const float4 z2 = *(const float4*)&zpre[off + 4];
        const float4 h1 = *(const float4*)&hfull[off];
        const float4 h2 = *(const float4*)&hfull[off + 4];
        float4 r1, r2;
        float zz;
        zz = 1.0f / (1.0f + __expf(-z1.x)); r1.x = zz * h1.x + (1.0f - zz) * tanhf(s1.x + o[0]);
        zz = 1.0f / (1.0f + __expf(-z1.y)); r1.y = zz * h1.y + (1.0f - zz) * tanhf(s1.y + o[1]);
        zz = 1.0f / (1.0f + __expf(-z1.z)); r1.z = zz * h1.z + (1.0f - zz) * tanhf(s1.z + o[2]);
        zz = 1.0f / (1.0f + __expf(-z1.w)); r1.w = zz * h1.w + (1.0f - zz) * tanhf(s1.w + o[3]);
        zz = 1.0f / (1.0f + __expf(-z2.x)); r2.x = zz * h2.x + (1.0f - zz) * tanhf(s2.x + o[4]);
        zz = 1.0f / (1.0f + __expf(-z2.y)); r2.y = zz * h2.y + (1.0f - zz) * tanhf(s2.y + o[5]);
        zz = 1.0f / (1.0f + __expf(-z2.z)); r2.z = zz * h2.z + (1.0f - zz) * tanhf(s2.z + o[6]);
        zz = 1.0f / (1.0f + __expf(-z2.w)); r2.w = zz * h2.w + (1.0f - zz) * tanhf(s2.w + o[7]);
        *(float4*)&tgt[off] = r1;
        *(float4*)&tgt[off + 4] = r2;
    }
}

// ---------------- launch ----------------

extern "C" void kernel_launch(void* const* d_in, const int* in_sizes, int n_in,
                              void* d_out, int out_size, void* d_ws, size_t ws_size,
                              hipStream_t stream) {
    const int N = N_NODES, E = N_EDGES;
    const float* x  = (const float*)d_in[0];
    const float* h  = (const float*)d_in[1];
    const int*  ei  = (const int*)d_in[2];
    const float* Wq = (const float*)d_in[3];
    const float* bq = (const float*)d_in[4];
    const float* Wk = (const float*)d_in[5];
    const float* bk = (const float*)d_in[6];
    const float* Wv = (const float*)d_in[7];
    const float* bv = (const float*)d_in[8];
    const float* Ws = (const float*)d_in[9];
    const float* bs = (const float*)d_in[10];
    float* out = (float*)d_out;

    const int* src = ei;
    const int* dst = ei + E;

    // ---- workspace layout ----
    char* w = (char*)d_ws;
    int* cnt    = (int*)w;                        // N
    int* colIdx = cnt + N;                        // N*CAP
    size_t intWords = (size_t)N + (size_t)N * CAP;
    char* p = w + ((intWords * 4 + 255) & ~(size_t)255);

    const size_t ND = (size_t)N * D;
    float* zpre  = (float*)p;            p += ND * 4;   // zskip -> zpre (final read in pass C)
    float* rskip = (float*)p;            p += ND * 4;   // rskip; later aliased as cskip
    float* ball  = (float*)p;            p += N_CONVS * 256 * 4;
    unsigned short* xb     = (unsigned short*)p; p += ND * 2;
    unsigned short* hb     = (unsigned short*)p; p += ND * 2;
    unsigned short* rhb    = (unsigned short*)p; p += ND * 2;
    unsigned short* qboth2 = (unsigned short*)p; p += ND * 2 * 4;  // [N][256] bf16 (q0..q3; reused by gemm45 @stride 128)
    unsigned char*  kv8a   = (unsigned char*)p;  p += (size_t)N_NODES * 256;
    unsigned char*  kv8b   = (unsigned char*)p;  p += (size_t)N_NODES * 256;
    unsigned short* WT     = (unsigned short*)p; p += (size_t)N_CONVS * 256 * 64 * 2;
    float* cskip = rskip;   // gemm45 runs after edge pass R consumed rskip

    const int NB_CVT = (int)(ND / 4 / 256);             // 6250 (exact)
    const int NB_PP = (N_CONVS * 256 * 64 + 255) / 256; // 384
    const int NB_GEMM = (N + 63) / 64;                  // 1563
    const int NB_FILL = ((E + CHUNK - 1) / CHUNK) * NPART;  // 245*8 = 1960
    const int NB_ATTN = (N + 31) / 32;                  // 3125

    prep_all<<<NB_CVT + NB_PP, 256, 0, stream>>>(x, h, xb, hb, Wq, Wk, Wv, Ws,
                                                 bq, bk, bv, bs, WT, ball, NB_CVT);
    hipMemsetAsync(cnt, 0, (size_t)N * sizeof(int), stream);
    fill_cap_part<<<NB_FILL, 256, 0, stream>>>(src, dst, E, cnt, colIdx);

#define WTc(i) (WT + (size_t)(i) * 256 * 64)
#define BLc(i) (ball + (size_t)(i) * 256)

    // convs 0..3 in one kernel (shared x/h staging)
    gemm_quad<<<NB_GEMM, 512, 0, stream>>>(
        xb, hb, N, WT, ball, qboth2, kv8a, kv8b, zpre, rskip);

    // pass Z: zpre += agg(conv0, conv1)
    edge_attn_t<0><<<NB_ATTN, 256, 0, stream>>>(
        cnt, colIdx, qboth2, 256, kv8a, nullptr, nullptr, nullptr, zpre, nullptr, N);

    // pass R: rhb = bf16(sigmoid(rskip + agg(conv2, conv3)) * h)   [rpre never stored]
    edge_attn_t<1><<<NB_ATTN, 256, 0, stream>>>(
        cnt, colIdx, qboth2 + 128, 256, kv8b, rskip, nullptr, h, nullptr, rhb, N);

    // convs 4,5 (inputs xb, rhb); q/kv reuse qboth2 (stride 128) and kv8a
    gemm_pair<<<NB_GEMM, 512, 0, stream>>>(
        xb, rhb, N, WTc(4), WTc(5), BLc(4), BLc(5), qboth2, kv8a, cskip);

    // pass C: out = z*h + (1-z)*tanh(cskip + agg(conv4, conv5)), z = sigmoid(zpre)
    edge_attn_t<2><<<NB_ATTN, 256, 0, stream>>>(
        cnt, colIdx, qboth2, 128, kv8a, cskip, zpre, h, out, nullptr, N);

#undef WTc
#undef BLc
}